// Round 6
// baseline (771.856 us; speedup 1.0000x reference)
//
#include <hip/hip_runtime.h>
#include <math.h>

#define KNN 20
#define NS 0.2f
#define EPSV 1e-6f
#define QT 4
#define OT 8
#define CROW 507   // 169*3, cat row stride (floats)
#define SSPLIT 8   // stats splits (== B; split s covers batch s exactly)

struct F3 { float x, y, z; };   // 12-byte vector load (global_load_dwordx3)

extern __shared__ __align__(16) float smem[];

// ---------------- transpose (B,N,3) -> (B,3,N) + fused sqnorm (layer-1) ----------------
__global__ void k_transpose(const float* __restrict__ x, float* __restrict__ xt,
                            float* __restrict__ xx, int B, int N) {
    int i = blockIdx.x * blockDim.x + threadIdx.x;
    if (i >= B * N) return;
    int b = i / N, n = i % N;
    const float* src = x + (size_t)(b * N + n) * 3;
    float* dst = xt + (size_t)b * 3 * N + n;
    float s0 = src[0], s1 = src[1], s2 = src[2];
    dst[0] = s0;
    dst[(size_t)N] = s1;
    dst[(size_t)2 * N] = s2;
    float s = 0.f;
    s += s0 * s0;
    s += s1 * s1;
    s += s2 * s2;
    xx[i] = s;
}

// ---------------- per-point squared norm (layers 2-4 knn input slice) ----------------
__global__ void k_sqnorm(const float* __restrict__ X, float* __restrict__ xx,
                         int N, int D, long batchStride, long sliceOff) {
    int i = blockIdx.x * 256 + threadIdx.x;
    int b = i / N, n = i % N;
    const float* Xb = X + (size_t)b * batchStride + sliceOff + n;
    float s = 0.f;
    for (int d = 0; d < D; ++d) {
        float v = Xb[(size_t)d * N];
        s += v * v;
    }
    xx[i] = s;
}

// ---------------- knn: 4 waves/block, wave-local top-k ----------------
// pd compute unchanged (bit-identical). Selection: per-lane sorted u64 keys
// (orderable-float || 1023-idx), Batcher-sorted once, then FIVE rounds each
// extracting FOUR winners: lanes contribute their top-4, a 6-step bitonic
// butterfly merges to the global top-4 (sorted desc, converged in all lanes),
// owners pop by count. Winner sequence == sequential argmax order
// (value desc, index asc) -> bit-identical indices. 4x shallower dependent-
// shuffle critical path than 1-per-butterfly extraction.
__global__ void k_knn(const float* __restrict__ X, const float* __restrict__ xx,
                      int* __restrict__ idx,
                      int N, int D, long batchStride, long sliceOff) {
    int b = blockIdx.y;
    int q0 = blockIdx.x * QT;
    int tid = threadIdx.x;
    int lane = tid & 63;
    int wave = tid >> 6;

    __shared__ __align__(16) float qf[128 * QT];   // [d][q], D <= 126
    __shared__ __align__(16) float pd[QT][1024];   // N == 1024

    const float* Xb = X + (size_t)b * batchStride + sliceOff;
    const float* xxb = xx + (size_t)b * N;

    for (int t = tid; t < QT * D; t += 256) {
        int d = t >> 2, q = t & 3;
        qf[d * QT + q] = Xb[(size_t)d * N + (q0 + q)];
    }
    __syncthreads();

    float a0x = 0.f, a0y = 0.f, a0z = 0.f, a0w = 0.f;
    float a1x = 0.f, a1y = 0.f, a1z = 0.f, a1w = 0.f;
    float a2x = 0.f, a2y = 0.f, a2z = 0.f, a2w = 0.f;
    float a3x = 0.f, a3y = 0.f, a3z = 0.f, a3w = 0.f;

    const float* mbase = Xb + 4 * tid;
#pragma unroll 3
    for (int d = 0; d < D; ++d) {
        float4 xm = *(const float4*)(mbase + (size_t)d * N);
        float4 qv = *(const float4*)(qf + d * QT);
        a0x += qv.x * xm.x; a0y += qv.x * xm.y; a0z += qv.x * xm.z; a0w += qv.x * xm.w;
        a1x += qv.y * xm.x; a1y += qv.y * xm.y; a1z += qv.y * xm.z; a1w += qv.y * xm.w;
        a2x += qv.z * xm.x; a2y += qv.z * xm.y; a2z += qv.z * xm.z; a2w += qv.z * xm.w;
        a3x += qv.w * xm.x; a3y += qv.w * xm.y; a3z += qv.w * xm.z; a3w += qv.w * xm.w;
    }

    {
        float4 m2 = *(const float4*)(xxb + 4 * tid);   // ||x_m||^2, 4 m's
        float4 qn = *(const float4*)(xxb + q0);        // ||x_q||^2, 4 q's
        float4 v;
        v.x = 2.f * a0x - qn.x - m2.x; v.y = 2.f * a0y - qn.x - m2.y;
        v.z = 2.f * a0z - qn.x - m2.z; v.w = 2.f * a0w - qn.x - m2.w;
        *(float4*)&pd[0][4 * tid] = v;
        v.x = 2.f * a1x - qn.y - m2.x; v.y = 2.f * a1y - qn.y - m2.y;
        v.z = 2.f * a1z - qn.y - m2.z; v.w = 2.f * a1w - qn.y - m2.w;
        *(float4*)&pd[1][4 * tid] = v;
        v.x = 2.f * a2x - qn.z - m2.x; v.y = 2.f * a2y - qn.z - m2.y;
        v.z = 2.f * a2z - qn.z - m2.z; v.w = 2.f * a2w - qn.z - m2.w;
        *(float4*)&pd[2][4 * tid] = v;
        v.x = 2.f * a3x - qn.w - m2.x; v.y = 2.f * a3y - qn.w - m2.y;
        v.z = 2.f * a3z - qn.w - m2.z; v.w = 2.f * a3w - qn.w - m2.w;
        *(float4*)&pd[3][4 * tid] = v;
    }
    __syncthreads();

    // ---- build sortable keys: hi = orderable(float bits), lo = 1023 - idx ----
    // u64 '>' == (value greater) || (value equal && index lower). Keys unique.
    unsigned long long key[16];
#pragma unroll
    for (int t = 0; t < 16; ++t) {
        unsigned u = __float_as_uint(pd[wave][t * 64 + lane]);
        u ^= (unsigned)((int)u >> 31) | 0x80000000u;
        unsigned lo = (unsigned)(1023 - t * 64) - (unsigned)lane;
        key[t] = ((unsigned long long)u << 32) | (unsigned long long)lo;
    }

    // ---- per-lane descending sort: explicit Batcher odd-even mergesort n=16 ----
#define CE(a, b)                                        \
    {                                                   \
        unsigned long long ka = key[a], kb = key[b];    \
        bool sw = ka < kb;                              \
        key[a] = sw ? kb : ka;                          \
        key[b] = sw ? ka : kb;                          \
    }
    CE(0,1) CE(2,3) CE(4,5) CE(6,7) CE(8,9) CE(10,11) CE(12,13) CE(14,15)
    CE(0,2) CE(1,3) CE(4,6) CE(5,7) CE(8,10) CE(9,11) CE(12,14) CE(13,15)
    CE(1,2) CE(5,6) CE(9,10) CE(13,14)
    CE(0,4) CE(1,5) CE(2,6) CE(3,7) CE(8,12) CE(9,13) CE(10,14) CE(11,15)
    CE(2,4) CE(3,5) CE(10,12) CE(11,13)
    CE(1,2) CE(3,4) CE(5,6) CE(9,10) CE(11,12) CE(13,14)
    CE(0,8) CE(1,9) CE(2,10) CE(3,11) CE(4,12) CE(5,13) CE(6,14) CE(7,15)
    CE(4,8) CE(5,9) CE(6,10) CE(7,11)
    CE(2,4) CE(3,5) CE(6,8) CE(7,9) CE(10,12) CE(11,13)
    CE(1,2) CE(3,4) CE(5,6) CE(7,8) CE(9,10) CE(11,12) CE(13,14)
#undef CE

    // ---- 5 rounds x 4 winners: bitonic-merge butterfly over lane top-4s ----
    long outBase = ((long)b * N + q0 + wave) * KNN;
#pragma unroll
    for (int r = 0; r < 5; ++r) {
        unsigned long long w0 = key[0], w1 = key[1], w2 = key[2], w3 = key[3];
#pragma unroll
        for (int off = 32; off >= 1; off >>= 1) {
            unsigned long long p0 = __shfl_xor(w0, off, 64);
            unsigned long long p1 = __shfl_xor(w1, off, 64);
            unsigned long long p2 = __shfl_xor(w2, off, 64);
            unsigned long long p3 = __shfl_xor(w3, off, 64);
            // [w0..w3 desc, p3..p0 asc] is bitonic; split stage:
            unsigned long long t0 = w0 > p3 ? w0 : p3;
            unsigned long long t1 = w1 > p2 ? w1 : p2;
            unsigned long long t2 = w2 > p1 ? w2 : p1;
            unsigned long long t3 = w3 > p0 ? w3 : p0;
            // bitonic sort-4 desc of (t0..t3):
            unsigned long long u0 = t0 > t2 ? t0 : t2;
            unsigned long long u2 = t0 > t2 ? t2 : t0;
            unsigned long long u1 = t1 > t3 ? t1 : t3;
            unsigned long long u3 = t1 > t3 ? t3 : t1;
            w0 = u0 > u1 ? u0 : u1;
            w1 = u0 > u1 ? u1 : u0;
            w2 = u2 > u3 ? u2 : u3;
            w3 = u2 > u3 ? u3 : u2;
        }
        // w0..w3 = global top-4 of remaining, sorted desc, same in all lanes
        if (lane == 0) {
            idx[outBase + 4 * r + 0] = 1023 - (int)(w0 & 1023u);
            idx[outBase + 4 * r + 1] = 1023 - (int)(w1 & 1023u);
            idx[outBase + 4 * r + 2] = 1023 - (int)(w2 & 1023u);
            idx[outBase + 4 * r + 3] = 1023 - (int)(w3 & 1023u);
        }
        if (r < 4) {
            // keys unique -> winner set == {k >= w3}; a lane's winners are its
            // first c keys (sorted desc). Pop via static shifts (c <= 4).
            int c = (int)(key[0] >= w3) + (int)(key[1] >= w3)
                  + (int)(key[2] >= w3) + (int)(key[3] >= w3);
            if (c & 1) {
#pragma unroll
                for (int t = 0; t < 15; ++t) key[t] = key[t + 1];
                key[15] = 0ull;
            }
            if (c & 2) {
#pragma unroll
                for (int t = 0; t < 14; ++t) key[t] = key[t + 2];
                key[14] = 0ull; key[15] = 0ull;
            }
            if (c & 4) {
#pragma unroll
                for (int t = 0; t < 12; ++t) key[t] = key[t + 4];
                key[12] = 0ull; key[13] = 0ull; key[14] = 0ull; key[15] = 0ull;
            }
        }
    }
}

// ---------------- LDS-staged point-major pair matmul ----------------
__global__ void k_matmul_pair_lds(const float* __restrict__ X, const float* __restrict__ W,
                                  const float* __restrict__ Dw,
                                  float* __restrict__ U, float* __restrict__ V,
                                  float* __restrict__ UD, float* __restrict__ VD,
                                  int C, int Co, int CoP, int TILE,
                                  int rowStride, int colOff) {
    const int CP = C * CoP;
    float* wts = smem;            // 4*CP: [WA | WB-WA | DA | DB-DA], each [c][o]
    float* xs = smem + 4 * CP;    // TILE * C * 3

    int tid = threadIdx.x;
    int bn0 = blockIdx.x * TILE;  // flattened b*N+n base
    int C3 = C * 3;

    // zero padded o-lanes
    int npad = CoP - Co;
    if (npad) {
        for (int t = tid; t < 4 * C * npad; t += 256) {
            int q = t / npad, oo = Co + t % npad;
            int mat = q / C, c = q % C;
            wts[mat * CP + c * CoP + oo] = 0.f;
        }
    }
    // stage raw weights (coalesced global reads, LDS transpose writes)
    int twoCC = 2 * C * Co;
    for (int t = tid; t < twoCC; t += 256) {
        int o = t / (2 * C), c = t % (2 * C);
        float w = W[t], dw = Dw[t];
        if (c < C) {
            wts[c * CoP + o] = w;
            wts[2 * CP + c * CoP + o] = dw;
        } else {
            wts[CP + (c - C) * CoP + o] = w;
            wts[3 * CP + (c - C) * CoP + o] = dw;
        }
    }
    // stage point rows (coalesced)
    for (int t = tid; t < TILE * C3; t += 256) {
        int p = t / C3, cc = t % C3;
        xs[t] = X[(size_t)(bn0 + p) * rowStride + colOff + cc];
    }
    __syncthreads();
    // WB -= WA, DB -= DA in place
    for (int t = tid; t < CP; t += 256) {
        wts[CP + t] -= wts[t];
        wts[3 * CP + t] -= wts[2 * CP + t];
    }
    __syncthreads();

    int GPP = CoP >> 2;
    int items = TILE * GPP;
    for (int e = tid; e < items; e += 256) {
        int p = e / GPP, og = e - p * GPP;
        int o0 = og * 4;
        const float* xr = xs + p * C3;

        float aU[4][3], aV[4][3], aDu[4][3], aDv[4][3];
#pragma unroll
        for (int i = 0; i < 4; ++i)
#pragma unroll
            for (int j = 0; j < 3; ++j) {
                aU[i][j] = 0.f; aV[i][j] = 0.f; aDu[i][j] = 0.f; aDv[i][j] = 0.f;
            }

        for (int c = 0; c < C; ++c) {
            float x0 = xr[c * 3], x1 = xr[c * 3 + 1], x2 = xr[c * 3 + 2];
            const float* wp = wts + c * CoP + o0;
            float4 wa4 = *(const float4*)(wp);
            float4 wb4 = *(const float4*)(wp + CP);
            float4 da4 = *(const float4*)(wp + 2 * CP);
            float4 db4 = *(const float4*)(wp + 3 * CP);
            float wav[4] = {wa4.x, wa4.y, wa4.z, wa4.w};
            float wbv[4] = {wb4.x, wb4.y, wb4.z, wb4.w};
            float dav[4] = {da4.x, da4.y, da4.z, da4.w};
            float dbv[4] = {db4.x, db4.y, db4.z, db4.w};
#pragma unroll
            for (int i = 0; i < 4; ++i) {
                aU[i][0] += wav[i] * x0; aU[i][1] += wav[i] * x1; aU[i][2] += wav[i] * x2;
                aV[i][0] += wbv[i] * x0; aV[i][1] += wbv[i] * x1; aV[i][2] += wbv[i] * x2;
                aDu[i][0] += dav[i] * x0; aDu[i][1] += dav[i] * x1; aDu[i][2] += dav[i] * x2;
                aDv[i][0] += dbv[i] * x0; aDv[i][1] += dbv[i] * x1; aDv[i][2] += dbv[i] * x2;
            }
        }

        size_t base = ((size_t)(bn0 + p) * Co + o0) * 3;
#pragma unroll
        for (int i = 0; i < 4; ++i) {
            int o = o0 + i;
            if (o < Co) {
                size_t off = base + (size_t)i * 3;
                U[off] = aU[i][0]; U[off + 1] = aU[i][1]; U[off + 2] = aU[i][2];
                V[off] = aV[i][0]; V[off + 1] = aV[i][1]; V[off + 2] = aV[i][2];
                UD[off] = aDu[i][0]; UD[off + 1] = aDu[i][1]; UD[off + 2] = aDu[i][2];
                VD[off] = aDv[i][0]; VD[off + 1] = aDv[i][1]; VD[off + 2] = aDv[i][2];
            }
        }
    }
}

// ---------------- BN stats stage A (deterministic, R5 order + LDS staging) ----------------
__global__ void k_stats_edge_det(const float* __restrict__ U, const float* __restrict__ V,
                                 const int* __restrict__ idx, float* __restrict__ partials,
                                 int N, int Co, int BN) {
    int o = blockIdx.x;
    int s = blockIdx.y;
    int tid = threadIdx.x;
    int P = BN / SSPLIT;      // == N == 1024
    int g0 = s * P;

    __shared__ float Ush[3072];   // N * 3 (channel-o vectors for batch s)
    __shared__ float r1[256], r2[256];

    for (int t = tid; t < P; t += 256) {
        F3 u3 = *(const F3*)(U + ((size_t)(g0 + t) * Co + o) * 3);
        Ush[t * 3 + 0] = u3.x;
        Ush[t * 3 + 1] = u3.y;
        Ush[t * 3 + 2] = u3.z;
    }
    __syncthreads();

    float s1 = 0.f, s2 = 0.f;
    for (int pl = tid; pl < P; pl += 256) {
        int g = g0 + pl;                       // flattened b*N+n
        F3 v3 = *(const F3*)(V + ((size_t)g * Co + o) * 3);
        float v0 = v3.x, v1 = v3.y, v2 = v3.z;
        const int* ip = idx + (size_t)g * KNN;
        for (int kk = 0; kk < KNN; ++kk) {
            const float* Ur = Ush + ip[kk] * 3;   // idx is batch-local
            float p0 = Ur[0] + v0;
            float p1 = Ur[1] + v1;
            float p2 = Ur[2] + v2;
            float nm = sqrtf(p0 * p0 + p1 * p1 + p2 * p2) + EPSV;
            s1 += nm;
            s2 += nm * nm;
        }
    }
    r1[tid] = s1; r2[tid] = s2;
    __syncthreads();
    for (int st = 128; st > 0; st >>= 1) {
        if (tid < st) { r1[tid] += r1[tid + st]; r2[tid] += r2[tid + st]; }
        __syncthreads();
    }
    if (tid == 0) {
        partials[(o * SSPLIT + s) * 2] = r1[0];
        partials[(o * SSPLIT + s) * 2 + 1] = r2[0];
    }
}

// ---------------- BN + dir leaky + mean-pool (fused stage-B), thread per (b,n,o) ----------------
__global__ void k_final_edge_p(const float* __restrict__ U, const float* __restrict__ V,
                               const float* __restrict__ UD, const float* __restrict__ VD,
                               const int* __restrict__ idx, const float* __restrict__ partials,
                               const float* __restrict__ gamma, const float* __restrict__ beta,
                               float* __restrict__ catp,
                               int N, int Co, int colOff, float cnt, int total) {
    int g = blockIdx.x * 256 + threadIdx.x;
    if (g >= total) return;
    int o = g % Co;
    int r = g / Co;
    int n = r % N;
    int b = r / N;

    float s1 = 0.f, s2 = 0.f;
    for (int s = 0; s < SSPLIT; ++s) {
        s1 += partials[(o * SSPLIT + s) * 2];
        s2 += partials[(o * SSPLIT + s) * 2 + 1];
    }
    float mu = s1 / cnt;
    float var = s2 / cnt - mu * mu;
    float inv = rsqrtf(var + 1e-5f);
    float gmm = gamma[o], bt = beta[o];

    size_t ctr = ((size_t)(b * N + n) * Co + o) * 3;
    F3 vc = *(const F3*)(V + ctr);
    F3 wc = *(const F3*)(VD + ctr);
    float v0 = vc.x, v1 = vc.y, v2 = vc.z;
    float w0 = wc.x, w1 = wc.y, w2 = wc.z;
    const int* ip = idx + ((size_t)b * N + n) * KNN;

    float a0 = 0.f, a1 = 0.f, a2 = 0.f;
    for (int kk = 0; kk < KNN; ++kk) {
        int m = ip[kk];
        size_t nb = ((size_t)(b * N + m) * Co + o) * 3;
        F3 un = *(const F3*)(U + nb);
        F3 dn = *(const F3*)(UD + nb);
        float p0 = un.x + v0;
        float p1 = un.y + v1;
        float p2 = un.z + v2;
        float nm = sqrtf(p0 * p0 + p1 * p1 + p2 * p2) + EPSV;
        float nbn = (nm - mu) * inv * gmm + bt;
        float sc = nbn / nm;
        p0 *= sc; p1 *= sc; p2 *= sc;
        float d0 = dn.x + w0;
        float d1 = dn.y + w1;
        float d2 = dn.z + w2;
        float dot = p0 * d0 + p1 * d1 + p2 * d2;
        if (dot >= 0.f) {
            a0 += p0; a1 += p1; a2 += p2;
        } else {
            float f = dot / (d0 * d0 + d1 * d1 + d2 * d2 + EPSV);
            a0 += NS * p0 + (1.f - NS) * (p0 - f * d0);
            a1 += NS * p1 + (1.f - NS) * (p1 - f * d1);
            a2 += NS * p2 + (1.f - NS) * (p2 - f * d2);
        }
    }
    const float invk = 1.f / (float)KNN;
    float* outp = catp + (size_t)(b * N + n) * CROW + colOff + o * 3;
    outp[0] = a0 * invk;
    outp[1] = a1 * invk;
    outp[2] = a2 * invk;
}

// ---------------- cat_p slice -> cat_n slice (LDS tiled transpose) ----------------
__global__ void k_transpose_cat(const float* __restrict__ catp, float* __restrict__ catn,
                                int N, int c0, int CC) {
    __shared__ float tile[32][33];
    int b = blockIdx.z;
    int n0 = blockIdx.x * 32;
    int cb = blockIdx.y * 32;
    int tid = threadIdx.x;
    int tx = tid & 31, ty = tid >> 5;   // 32 x 8

#pragma unroll
    for (int rr = 0; rr < 4; ++rr) {
        int nl = ty + rr * 8;
        int c = cb + tx;
        if (c < CC)
            tile[nl][tx] = catp[(size_t)(b * N + n0 + nl) * CROW + c0 + c];
    }
    __syncthreads();
#pragma unroll
    for (int rr = 0; rr < 4; ++rr) {
        int cl = ty + rr * 8;
        int c = cb + cl;
        if (c < CC)
            catn[(size_t)b * CROW * N + (size_t)(c0 + c) * N + n0 + tx] = tile[tx][cl];
    }
}

// ---------------- plain matmul (layer 5, n-major): U = W*x, j-fused ----------------
__global__ void k_matmul_plain(const float* __restrict__ X, const float* __restrict__ W,
                               float* __restrict__ U,
                               int N, int Cin, int Cout, long batchStride, long sliceOff) {
    int ot = blockIdx.y;
    int b = blockIdx.z;
    int o0 = ot * OT;
    int tid = threadIdx.x;
    int n = blockIdx.x * 256 + tid;

    __shared__ __align__(16) float wsm[OT][176];  // Cin <= 169; stride 176 keeps rows 16B-aligned
    for (int t = tid; t < OT * Cin; t += 256) {
        int oo = t / Cin, c = t % Cin;
        int o = o0 + oo;
        wsm[oo][c] = (o < Cout) ? W[(size_t)o * Cin + c] : 0.f;
    }
    __syncthreads();

    const float* Xp = X + (size_t)b * batchStride + sliceOff + n;
    float au[OT][3];
#pragma unroll
    for (int oo = 0; oo < OT; ++oo) {
        au[oo][0] = 0.f; au[oo][1] = 0.f; au[oo][2] = 0.f;
    }

    int c = 0;
    for (; c + 4 <= Cin; c += 4) {
        float x0[3], x1[3], x2[3], x3[3];
        {
            const float* xc = Xp + (size_t)(c + 0) * 3 * N;
            x0[0] = xc[0]; x0[1] = xc[(size_t)N]; x0[2] = xc[(size_t)2 * N];
            xc = Xp + (size_t)(c + 1) * 3 * N;
            x1[0] = xc[0]; x1[1] = xc[(size_t)N]; x1[2] = xc[(size_t)2 * N];
            xc = Xp + (size_t)(c + 2) * 3 * N;
            x2[0] = xc[0]; x2[1] = xc[(size_t)N]; x2[2] = xc[(size_t)2 * N];
            xc = Xp + (size_t)(c + 3) * 3 * N;
            x3[0] = xc[0]; x3[1] = xc[(size_t)N]; x3[2] = xc[(size_t)2 * N];
        }
#pragma unroll
        for (int oo = 0; oo < OT; ++oo) {
            float4 w4 = *(const float4*)&wsm[oo][c];
#pragma unroll
            for (int j = 0; j < 3; ++j) {
                au[oo][j] += w4.x * x0[j];
                au[oo][j] += w4.y * x1[j];
                au[oo][j] += w4.z * x2[j];
                au[oo][j] += w4.w * x3[j];
            }
        }
    }
    for (; c < Cin; ++c) {
        const float* xc = Xp + (size_t)c * 3 * N;
        float xv[3] = {xc[0], xc[(size_t)N], xc[(size_t)2 * N]};
#pragma unroll
        for (int oo = 0; oo < OT; ++oo) {
            float wv = wsm[oo][c];
#pragma unroll
            for (int j = 0; j < 3; ++j) au[oo][j] += wv * xv[j];
        }
    }
#pragma unroll
    for (int oo = 0; oo < OT; ++oo) {
        int o = o0 + oo;
        if (o < Cout) {
#pragma unroll
            for (int j = 0; j < 3; ++j)
                U[(((size_t)b * Cout + o) * 3 + j) * N + n] = au[oo][j];
        }
    }
}

// ---------------- layer-5 stats (deterministic): one block per channel ----------------
__global__ void k_stats_plain_det(const float* __restrict__ U, float* __restrict__ mv,
                                  int N, int Cout, int BN, float cnt) {
    int o = blockIdx.x;
    int tid = threadIdx.x;
    float s1 = 0.f, s2 = 0.f;
    for (int g = tid; g < BN; g += 256) {
        int b = g / N, n = g % N;
        const float* Ub = U + (((size_t)b * Cout + o) * 3) * N;
        float p0 = Ub[n], p1 = Ub[(size_t)N + n], p2 = Ub[(size_t)2 * N + n];
        float nm = sqrtf(p0 * p0 + p1 * p1 + p2 * p2) + EPSV;
        s1 += nm;
        s2 += nm * nm;
    }
    __shared__ float r1[256], r2[256];
    r1[tid] = s1; r2[tid] = s2;
    __syncthreads();
    for (int st = 128; st > 0; st >>= 1) {
        if (tid < st) { r1[tid] += r1[tid + st]; r2[tid] += r2[tid + st]; }
        __syncthreads();
    }
    if (tid == 0) {
        float mu = r1[0] / cnt;
        float var = r2[0] / cnt - mu * mu;
        mv[2 * o] = mu;
        mv[2 * o + 1] = rsqrtf(var + 1e-5f);
    }
}

// ---------------- layer-5 final: BN + dir leaky (1 dir channel) -> d_out ----------------
__global__ void k_final_plain(const float* __restrict__ U, const float* __restrict__ Dv,
                              const float* __restrict__ mv,
                              const float* __restrict__ gamma, const float* __restrict__ beta,
                              float* __restrict__ out, int N, int Cout) {
    int b = blockIdx.z, o = blockIdx.y, tid = threadIdx.x;
    int n = blockIdx.x * 256 + tid;
    float mu = mv[2 * o];
    float inv = mv[2 * o + 1];
    float g = gamma[o], bt = beta[o];

    const float* Ub = U + (((size_t)b * Cout + o) * 3) * N;
    float p0 = Ub[n], p1 = Ub[(size_t)N + n], p2 = Ub[(size_t)2 * N + n];
    float nm = sqrtf(p0 * p0 + p1 * p1 + p2 * p2) + EPSV;
    float nbn = (nm - mu) * inv * g + bt;
    float sc = nbn / nm;
    p0 *= sc; p1 *= sc; p2 *= sc;

    float d0 = Dv[((size_t)b * 3 + 0) * N + n];
    float d1 = Dv[((size_t)b * 3 + 1) * N + n];
    float d2 = Dv[((size_t)b * 3 + 2) * N + n];
    float dot = p0 * d0 + p1 * d1 + p2 * d2;
    float o0, o1, o2;
    if (dot >= 0.f) {
        o0 = p0; o1 = p1; o2 = p2;
    } else {
        float f = dot / (d0 * d0 + d1 * d1 + d2 * d2 + EPSV);
        o0 = NS * p0 + (1.f - NS) * (p0 - f * d0);
        o1 = NS * p1 + (1.f - NS) * (p1 - f * d1);
        o2 = NS * p2 + (1.f - NS) * (p2 - f * d2);
    }
    size_t ob = (((size_t)b * Cout + o) * 3) * N + n;
    out[ob] = o0;
    out[ob + (size_t)N] = o1;
    out[ob + (size_t)2 * N] = o2;
}

extern "C" void kernel_launch(void* const* d_in, const int* in_sizes, int n_in,
                              void* d_out, int out_size, void* d_ws, size_t ws_size,
                              hipStream_t stream) {
    (void)in_sizes; (void)n_in; (void)out_size; (void)ws_size;
    const int B = 8, N = 1024;

    const float* x = (const float*)d_in[0];
    const float* W[5]; const float* Dw[5]; const float* G[5]; const float* Bt[5];
    for (int l = 0; l < 5; ++l) {
        W[l]  = (const float*)d_in[1 + 4 * l];
        Dw[l] = (const float*)d_in[2 + 4 * l];
        G[l]  = (const float*)d_in[3 + 4 * l];
        Bt[l] = (const float*)d_in[4 + 4 * l];
    }

    float* ws = (float*)d_ws;
    size_t off = 0;
    float* xt = ws + off;     off += (size_t)B * 3 * N;
    int* idx = (int*)(ws + off); off += (size_t)B * N * KNN;
    float* catp = ws + off;   off += (size_t)B * N * CROW;
    float* catn = ws + off;   off += (size_t)B * N * CROW;
    float* Up = ws + off;     off += (size_t)B * N * 85 * 3;
    float* Vp = ws + off;     off += (size_t)B * N * 85 * 3;
    float* UDp = ws + off;    off += (size_t)B * N * 85 * 3;
    float* VDp = ws + off;    off += (size_t)B * N * 85 * 3;
    float* U5 = ws + off;     off += (size_t)B * 341 * 3 * N;
    float* d5buf = ws + off;  off += (size_t)B * 3 * N;
    float* xx = ws + off;     off += (size_t)B * N;           // 16B-aligned (all prior multiples of 4)
    float* partials = ws + off; off += (size_t)341 * SSPLIT * 2;
    float* mv = ws + off;     off += 2 * 341;

    k_transpose<<<(B * N + 255) / 256, 256, 0, stream>>>(x, xt, xx, B, N);

    const int Cin_[4]  = {1, 21, 21, 42};
    const int Cout_[4] = {21, 21, 42, 85};
    const int inOff_[4] = {-1, 0, 21, 42};
    const int outOff_[4] = {0, 21, 42, 84};
    const int Tile_[4] = {32, 32, 32, 8};   // LDS budget: L4 needs small x-tile

    const int BN = B * N;

    for (int l = 0; l < 4; ++l) {
        int C = Cin_[l], Co = Cout_[l];
        int D = C * 3;
        int CoP = (Co + 3) & ~3;
        int TILE = Tile_[l];

        // n-major source for knn
        const float* Xn; long bs, so;
        if (inOff_[l] < 0) { Xn = xt; bs = (long)3 * N; so = 0; }
        else { Xn = catn; bs = (long)CROW * N; so = (long)inOff_[l] * 3 * N; }

        // point-major source for matmul
        const float* Xp; int rs, co;
        if (inOff_[l] < 0) { Xp = x; rs = 3; co = 0; }
        else { Xp = catp; rs = CROW; co = inOff_[l] * 3; }

        // hoisted sqnorms (layer 1 fused into k_transpose)
        if (inOff_[l] >= 0)
            k_sqnorm<<<(B * N) / 256, 256, 0, stream>>>(Xn, xx, N, D, bs, so);

        dim3 gk(N / QT, B);
        k_knn<<<gk, 256, 0, stream>>>(Xn, xx, idx, N, D, bs, so);

        size_t smemB = (size_t)(4 * C * CoP + TILE * C * 3) * sizeof(float);
        k_matmul_pair_lds<<<(B * N) / TILE, 256, smemB, stream>>>(
            Xp, W[l], Dw[l], Up, Vp, UDp, VDp, C, Co, CoP, TILE, rs, co);

        dim3 gst(Co, SSPLIT);
        k_stats_edge_det<<<gst, 256, 0, stream>>>(Up, Vp, idx, partials, N, Co, BN);

        int total = BN * Co;
        k_final_edge_p<<<(total + 255) / 256, 256, 0, stream>>>(
            Up, Vp, UDp, VDp, idx, partials, G[l], Bt[l], catp,
            N, Co, outOff_[l] * 3, (float)((size_t)BN * KNN), total);

        int CC = Co * 3;
        dim3 gt(N / 32, (CC + 31) / 32, B);
        k_transpose_cat<<<gt, 256, 0, stream>>>(catp, catn, N, outOff_[l] * 3, CC);
    }

    // layer 5 (reads catn n-major)
    {
        long bs = (long)CROW * N, so = 0;
        dim3 gm5(N / 256, (341 + OT - 1) / OT, B);
        k_matmul_plain<<<gm5, 256, 0, stream>>>(catn, W[4], U5, N, 169, 341, bs, so);
        dim3 gmd(N / 256, 1, B);
        k_matmul_plain<<<gmd, 256, 0, stream>>>(catn, Dw[4], d5buf, N, 169, 1, bs, so);
        k_stats_plain_det<<<341, 256, 0, stream>>>(U5, mv, N, 341, BN, (float)BN);
        dim3 gs5(N / 256, 341, B);
        k_final_plain<<<gs5, 256, 0, stream>>>(U5, d5buf, mv, G[4], Bt[4],
                                               (float*)d_out, N, 341);
    }
}

// Round 7
// 758.556 us; speedup vs baseline: 1.0175x; 1.0175x over previous
//
#include <hip/hip_runtime.h>
#include <math.h>

#define KNN 20
#define NS 0.2f
#define EPSV 1e-6f
#define QT 4
#define OT 8
#define CROW 507   // 169*3, cat row stride (floats)
#define SSPLIT 8   // stats splits (== B; split s covers batch s exactly)

struct F3 { float x, y, z; };   // 12-byte vector load (global_load_dwordx3)

extern __shared__ __align__(16) float smem[];

// ---------------- transpose (B,N,3) -> (B,3,N) + fused sqnorm (layer-1) ----------------
__global__ void k_transpose(const float* __restrict__ x, float* __restrict__ xt,
                            float* __restrict__ xx, int B, int N) {
    int i = blockIdx.x * blockDim.x + threadIdx.x;
    if (i >= B * N) return;
    int b = i / N, n = i % N;
    const float* src = x + (size_t)(b * N + n) * 3;
    float* dst = xt + (size_t)b * 3 * N + n;
    float s0 = src[0], s1 = src[1], s2 = src[2];
    dst[0] = s0;
    dst[(size_t)N] = s1;
    dst[(size_t)2 * N] = s2;
    float s = 0.f;
    s += s0 * s0;
    s += s1 * s1;
    s += s2 * s2;
    xx[i] = s;
}

// ---------------- per-point squared norm (layers 2-4 knn input slice) ----------------
__global__ void k_sqnorm(const float* __restrict__ X, float* __restrict__ xx,
                         int N, int D, long batchStride, long sliceOff) {
    int i = blockIdx.x * 256 + threadIdx.x;
    int b = i / N, n = i % N;
    const float* Xb = X + (size_t)b * batchStride + sliceOff + n;
    float s = 0.f;
    for (int d = 0; d < D; ++d) {
        float v = Xb[(size_t)d * N];
        s += v * v;
    }
    xx[i] = s;
}

// ---------------- knn: 4 waves/block, wave-local top-k (R3 selection, best measured) ----
// pd compute unchanged (bit-identical). Selection: per-lane sorted u64 keys
// (orderable-float || 1023-idx), Batcher-sorted once (explicit 63-CE network),
// then 20 extractions of {u64 max-butterfly + owner head-pop}. Same
// (value desc, index asc) total order as iterative argmax -> bit-identical.
__global__ void k_knn(const float* __restrict__ X, const float* __restrict__ xx,
                      int* __restrict__ idx,
                      int N, int D, long batchStride, long sliceOff) {
    int b = blockIdx.y;
    int q0 = blockIdx.x * QT;
    int tid = threadIdx.x;
    int lane = tid & 63;
    int wave = tid >> 6;

    __shared__ __align__(16) float qf[128 * QT];   // [d][q], D <= 126
    __shared__ __align__(16) float pd[QT][1024];   // N == 1024

    const float* Xb = X + (size_t)b * batchStride + sliceOff;
    const float* xxb = xx + (size_t)b * N;

    for (int t = tid; t < QT * D; t += 256) {
        int d = t >> 2, q = t & 3;
        qf[d * QT + q] = Xb[(size_t)d * N + (q0 + q)];
    }
    __syncthreads();

    float a0x = 0.f, a0y = 0.f, a0z = 0.f, a0w = 0.f;
    float a1x = 0.f, a1y = 0.f, a1z = 0.f, a1w = 0.f;
    float a2x = 0.f, a2y = 0.f, a2z = 0.f, a2w = 0.f;
    float a3x = 0.f, a3y = 0.f, a3z = 0.f, a3w = 0.f;

    const float* mbase = Xb + 4 * tid;
#pragma unroll 3
    for (int d = 0; d < D; ++d) {
        float4 xm = *(const float4*)(mbase + (size_t)d * N);
        float4 qv = *(const float4*)(qf + d * QT);
        a0x += qv.x * xm.x; a0y += qv.x * xm.y; a0z += qv.x * xm.z; a0w += qv.x * xm.w;
        a1x += qv.y * xm.x; a1y += qv.y * xm.y; a1z += qv.y * xm.z; a1w += qv.y * xm.w;
        a2x += qv.z * xm.x; a2y += qv.z * xm.y; a2z += qv.z * xm.z; a2w += qv.z * xm.w;
        a3x += qv.w * xm.x; a3y += qv.w * xm.y; a3z += qv.w * xm.z; a3w += qv.w * xm.w;
    }

    {
        float4 m2 = *(const float4*)(xxb + 4 * tid);   // ||x_m||^2, 4 m's
        float4 qn = *(const float4*)(xxb + q0);        // ||x_q||^2, 4 q's
        float4 v;
        v.x = 2.f * a0x - qn.x - m2.x; v.y = 2.f * a0y - qn.x - m2.y;
        v.z = 2.f * a0z - qn.x - m2.z; v.w = 2.f * a0w - qn.x - m2.w;
        *(float4*)&pd[0][4 * tid] = v;
        v.x = 2.f * a1x - qn.y - m2.x; v.y = 2.f * a1y - qn.y - m2.y;
        v.z = 2.f * a1z - qn.y - m2.z; v.w = 2.f * a1w - qn.y - m2.w;
        *(float4*)&pd[1][4 * tid] = v;
        v.x = 2.f * a2x - qn.z - m2.x; v.y = 2.f * a2y - qn.z - m2.y;
        v.z = 2.f * a2z - qn.z - m2.z; v.w = 2.f * a2w - qn.z - m2.w;
        *(float4*)&pd[2][4 * tid] = v;
        v.x = 2.f * a3x - qn.w - m2.x; v.y = 2.f * a3y - qn.w - m2.y;
        v.z = 2.f * a3z - qn.w - m2.z; v.w = 2.f * a3w - qn.w - m2.w;
        *(float4*)&pd[3][4 * tid] = v;
    }
    __syncthreads();

    // ---- build sortable keys: hi = orderable(float bits), lo = 1023 - idx ----
    unsigned long long key[16];
#pragma unroll
    for (int t = 0; t < 16; ++t) {
        unsigned u = __float_as_uint(pd[wave][t * 64 + lane]);
        u ^= (unsigned)((int)u >> 31) | 0x80000000u;
        unsigned lo = (unsigned)(1023 - t * 64) - (unsigned)lane;
        key[t] = ((unsigned long long)u << 32) | (unsigned long long)lo;
    }

    // ---- per-lane descending sort: explicit Batcher odd-even mergesort n=16 ----
#define CE(a, b)                                        \
    {                                                   \
        unsigned long long ka = key[a], kb = key[b];    \
        bool sw = ka < kb;                              \
        key[a] = sw ? kb : ka;                          \
        key[b] = sw ? ka : kb;                          \
    }
    CE(0,1) CE(2,3) CE(4,5) CE(6,7) CE(8,9) CE(10,11) CE(12,13) CE(14,15)
    CE(0,2) CE(1,3) CE(4,6) CE(5,7) CE(8,10) CE(9,11) CE(12,14) CE(13,15)
    CE(1,2) CE(5,6) CE(9,10) CE(13,14)
    CE(0,4) CE(1,5) CE(2,6) CE(3,7) CE(8,12) CE(9,13) CE(10,14) CE(11,15)
    CE(2,4) CE(3,5) CE(10,12) CE(11,13)
    CE(1,2) CE(3,4) CE(5,6) CE(9,10) CE(11,12) CE(13,14)
    CE(0,8) CE(1,9) CE(2,10) CE(3,11) CE(4,12) CE(5,13) CE(6,14) CE(7,15)
    CE(4,8) CE(5,9) CE(6,10) CE(7,11)
    CE(2,4) CE(3,5) CE(6,8) CE(7,9) CE(10,12) CE(11,13)
    CE(1,2) CE(3,4) CE(5,6) CE(7,8) CE(9,10) CE(11,12) CE(13,14)
#undef CE

    // ---- 20 extractions: u64 max-butterfly + owner head-pop ----
    long outBase = ((long)b * N + q0 + wave) * KNN;
    for (int it = 0; it < KNN; ++it) {
        unsigned long long bk = key[0];
#pragma unroll
        for (int off = 32; off >= 1; off >>= 1) {
            unsigned long long ok = __shfl_xor(bk, off, 64);
            if (ok > bk) bk = ok;
        }
        int bi = 1023 - (int)(bk & 1023u);
        if (lane == 0) idx[outBase + it] = bi;
        if ((bi & 63) == lane) {
#pragma unroll
            for (int t = 0; t < 15; ++t) key[t] = key[t + 1];
            key[15] = 0ull;   // sentinel: below every real key (ord(finite) >= 0x00800000)
        }
    }
}

// ---------------- LDS-staged point-major pair matmul ----------------
__global__ void k_matmul_pair_lds(const float* __restrict__ X, const float* __restrict__ W,
                                  const float* __restrict__ Dw,
                                  float* __restrict__ U, float* __restrict__ V,
                                  float* __restrict__ UD, float* __restrict__ VD,
                                  int C, int Co, int CoP, int TILE,
                                  int rowStride, int colOff) {
    const int CP = C * CoP;
    float* wts = smem;            // 4*CP: [WA | WB-WA | DA | DB-DA], each [c][o]
    float* xs = smem + 4 * CP;    // TILE * C * 3

    int tid = threadIdx.x;
    int bn0 = blockIdx.x * TILE;  // flattened b*N+n base
    int C3 = C * 3;

    // zero padded o-lanes
    int npad = CoP - Co;
    if (npad) {
        for (int t = tid; t < 4 * C * npad; t += 256) {
            int q = t / npad, oo = Co + t % npad;
            int mat = q / C, c = q % C;
            wts[mat * CP + c * CoP + oo] = 0.f;
        }
    }
    // stage raw weights (coalesced global reads, LDS transpose writes)
    int twoCC = 2 * C * Co;
    for (int t = tid; t < twoCC; t += 256) {
        int o = t / (2 * C), c = t % (2 * C);
        float w = W[t], dw = Dw[t];
        if (c < C) {
            wts[c * CoP + o] = w;
            wts[2 * CP + c * CoP + o] = dw;
        } else {
            wts[CP + (c - C) * CoP + o] = w;
            wts[3 * CP + (c - C) * CoP + o] = dw;
        }
    }
    // stage point rows (coalesced)
    for (int t = tid; t < TILE * C3; t += 256) {
        int p = t / C3, cc = t % C3;
        xs[t] = X[(size_t)(bn0 + p) * rowStride + colOff + cc];
    }
    __syncthreads();
    // WB -= WA, DB -= DA in place
    for (int t = tid; t < CP; t += 256) {
        wts[CP + t] -= wts[t];
        wts[3 * CP + t] -= wts[2 * CP + t];
    }
    __syncthreads();

    int GPP = CoP >> 2;
    int items = TILE * GPP;
    for (int e = tid; e < items; e += 256) {
        int p = e / GPP, og = e - p * GPP;
        int o0 = og * 4;
        const float* xr = xs + p * C3;

        float aU[4][3], aV[4][3], aDu[4][3], aDv[4][3];
#pragma unroll
        for (int i = 0; i < 4; ++i)
#pragma unroll
            for (int j = 0; j < 3; ++j) {
                aU[i][j] = 0.f; aV[i][j] = 0.f; aDu[i][j] = 0.f; aDv[i][j] = 0.f;
            }

        for (int c = 0; c < C; ++c) {
            float x0 = xr[c * 3], x1 = xr[c * 3 + 1], x2 = xr[c * 3 + 2];
            const float* wp = wts + c * CoP + o0;
            float4 wa4 = *(const float4*)(wp);
            float4 wb4 = *(const float4*)(wp + CP);
            float4 da4 = *(const float4*)(wp + 2 * CP);
            float4 db4 = *(const float4*)(wp + 3 * CP);
            float wav[4] = {wa4.x, wa4.y, wa4.z, wa4.w};
            float wbv[4] = {wb4.x, wb4.y, wb4.z, wb4.w};
            float dav[4] = {da4.x, da4.y, da4.z, da4.w};
            float dbv[4] = {db4.x, db4.y, db4.z, db4.w};
#pragma unroll
            for (int i = 0; i < 4; ++i) {
                aU[i][0] += wav[i] * x0; aU[i][1] += wav[i] * x1; aU[i][2] += wav[i] * x2;
                aV[i][0] += wbv[i] * x0; aV[i][1] += wbv[i] * x1; aV[i][2] += wbv[i] * x2;
                aDu[i][0] += dav[i] * x0; aDu[i][1] += dav[i] * x1; aDu[i][2] += dav[i] * x2;
                aDv[i][0] += dbv[i] * x0; aDv[i][1] += dbv[i] * x1; aDv[i][2] += dbv[i] * x2;
            }
        }

        size_t base = ((size_t)(bn0 + p) * Co + o0) * 3;
#pragma unroll
        for (int i = 0; i < 4; ++i) {
            int o = o0 + i;
            if (o < Co) {
                size_t off = base + (size_t)i * 3;
                U[off] = aU[i][0]; U[off + 1] = aU[i][1]; U[off + 2] = aU[i][2];
                V[off] = aV[i][0]; V[off + 1] = aV[i][1]; V[off + 2] = aV[i][2];
                UD[off] = aDu[i][0]; UD[off + 1] = aDu[i][1]; UD[off + 2] = aDu[i][2];
                VD[off] = aDv[i][0]; VD[off + 1] = aDv[i][1]; VD[off + 2] = aDv[i][2];
            }
        }
    }
}

// ---------------- BN stats stage A (deterministic, R5 order + LDS staging) ----------------
__global__ void k_stats_edge_det(const float* __restrict__ U, const float* __restrict__ V,
                                 const int* __restrict__ idx, float* __restrict__ partials,
                                 int N, int Co, int BN) {
    int o = blockIdx.x;
    int s = blockIdx.y;
    int tid = threadIdx.x;
    int P = BN / SSPLIT;      // == N == 1024
    int g0 = s * P;

    __shared__ float Ush[3072];   // N * 3 (channel-o vectors for batch s)
    __shared__ float r1[256], r2[256];

    for (int t = tid; t < P; t += 256) {
        F3 u3 = *(const F3*)(U + ((size_t)(g0 + t) * Co + o) * 3);
        Ush[t * 3 + 0] = u3.x;
        Ush[t * 3 + 1] = u3.y;
        Ush[t * 3 + 2] = u3.z;
    }
    __syncthreads();

    float s1 = 0.f, s2 = 0.f;
    for (int pl = tid; pl < P; pl += 256) {
        int g = g0 + pl;                       // flattened b*N+n
        F3 v3 = *(const F3*)(V + ((size_t)g * Co + o) * 3);
        float v0 = v3.x, v1 = v3.y, v2 = v3.z;
        const int* ip = idx + (size_t)g * KNN;
        for (int kk = 0; kk < KNN; ++kk) {
            const float* Ur = Ush + ip[kk] * 3;   // idx is batch-local
            float p0 = Ur[0] + v0;
            float p1 = Ur[1] + v1;
            float p2 = Ur[2] + v2;
            float nm = sqrtf(p0 * p0 + p1 * p1 + p2 * p2) + EPSV;
            s1 += nm;
            s2 += nm * nm;
        }
    }
    r1[tid] = s1; r2[tid] = s2;
    __syncthreads();
    for (int st = 128; st > 0; st >>= 1) {
        if (tid < st) { r1[tid] += r1[tid + st]; r2[tid] += r2[tid + st]; }
        __syncthreads();
    }
    if (tid == 0) {
        partials[(o * SSPLIT + s) * 2] = r1[0];
        partials[(o * SSPLIT + s) * 2 + 1] = r2[0];
    }
}

// ---------------- BN + dir leaky + mean-pool (fused stage-B), thread per (b,n,o) ----------------
__global__ void k_final_edge_p(const float* __restrict__ U, const float* __restrict__ V,
                               const float* __restrict__ UD, const float* __restrict__ VD,
                               const int* __restrict__ idx, const float* __restrict__ partials,
                               const float* __restrict__ gamma, const float* __restrict__ beta,
                               float* __restrict__ catp,
                               int N, int Co, int colOff, float cnt, int total) {
    int g = blockIdx.x * 256 + threadIdx.x;
    if (g >= total) return;
    int o = g % Co;
    int r = g / Co;
    int n = r % N;
    int b = r / N;

    float s1 = 0.f, s2 = 0.f;
    for (int s = 0; s < SSPLIT; ++s) {
        s1 += partials[(o * SSPLIT + s) * 2];
        s2 += partials[(o * SSPLIT + s) * 2 + 1];
    }
    float mu = s1 / cnt;
    float var = s2 / cnt - mu * mu;
    float inv = rsqrtf(var + 1e-5f);
    float gmm = gamma[o], bt = beta[o];

    size_t ctr = ((size_t)(b * N + n) * Co + o) * 3;
    F3 vc = *(const F3*)(V + ctr);
    F3 wc = *(const F3*)(VD + ctr);
    float v0 = vc.x, v1 = vc.y, v2 = vc.z;
    float w0 = wc.x, w1 = wc.y, w2 = wc.z;
    const int* ip = idx + ((size_t)b * N + n) * KNN;

    float a0 = 0.f, a1 = 0.f, a2 = 0.f;
    for (int kk = 0; kk < KNN; ++kk) {
        int m = ip[kk];
        size_t nb = ((size_t)(b * N + m) * Co + o) * 3;
        F3 un = *(const F3*)(U + nb);
        F3 dn = *(const F3*)(UD + nb);
        float p0 = un.x + v0;
        float p1 = un.y + v1;
        float p2 = un.z + v2;
        float nm = sqrtf(p0 * p0 + p1 * p1 + p2 * p2) + EPSV;
        float nbn = (nm - mu) * inv * gmm + bt;
        float sc = nbn / nm;
        p0 *= sc; p1 *= sc; p2 *= sc;
        float d0 = dn.x + w0;
        float d1 = dn.y + w1;
        float d2 = dn.z + w2;
        float dot = p0 * d0 + p1 * d1 + p2 * d2;
        if (dot >= 0.f) {
            a0 += p0; a1 += p1; a2 += p2;
        } else {
            float f = dot / (d0 * d0 + d1 * d1 + d2 * d2 + EPSV);
            a0 += NS * p0 + (1.f - NS) * (p0 - f * d0);
            a1 += NS * p1 + (1.f - NS) * (p1 - f * d1);
            a2 += NS * p2 + (1.f - NS) * (p2 - f * d2);
        }
    }
    const float invk = 1.f / (float)KNN;
    float* outp = catp + (size_t)(b * N + n) * CROW + colOff + o * 3;
    outp[0] = a0 * invk;
    outp[1] = a1 * invk;
    outp[2] = a2 * invk;
}

// ---------------- cat_p slice -> cat_n slice (LDS tiled transpose) ----------------
__global__ void k_transpose_cat(const float* __restrict__ catp, float* __restrict__ catn,
                                int N, int c0, int CC) {
    __shared__ float tile[32][33];
    int b = blockIdx.z;
    int n0 = blockIdx.x * 32;
    int cb = blockIdx.y * 32;
    int tid = threadIdx.x;
    int tx = tid & 31, ty = tid >> 5;   // 32 x 8

#pragma unroll
    for (int rr = 0; rr < 4; ++rr) {
        int nl = ty + rr * 8;
        int c = cb + tx;
        if (c < CC)
            tile[nl][tx] = catp[(size_t)(b * N + n0 + nl) * CROW + c0 + c];
    }
    __syncthreads();
#pragma unroll
    for (int rr = 0; rr < 4; ++rr) {
        int cl = ty + rr * 8;
        int c = cb + cl;
        if (c < CC)
            catn[(size_t)b * CROW * N + (size_t)(c0 + c) * N + n0 + tx] = tile[tx][cl];
    }
}

// ---------------- plain matmul (layer 5, n-major): U = W*x, j-fused + 2-n tile ----------
// Each thread computes OT outputs x 3 components x TWO n's (float2 x-loads).
// One ds_read_b128 weight read feeds 24 FMAs; global load instrs halve vs 1-n.
// Per-(o,j,n) accumulation: one FMA per c, strict ascending c, chunk order
// (c,c+1,c+2,c+3) identical to previous version -> bit-identical.
__global__ void k_matmul_plain(const float* __restrict__ X, const float* __restrict__ W,
                               float* __restrict__ U,
                               int N, int Cin, int Cout, long batchStride, long sliceOff) {
    int ot = blockIdx.y;
    int b = blockIdx.z;
    int o0 = ot * OT;
    int tid = threadIdx.x;
    int n = blockIdx.x * 512 + 2 * tid;

    __shared__ __align__(16) float wsm[OT][176];  // Cin <= 169; stride 176 keeps rows 16B-aligned
    for (int t = tid; t < OT * Cin; t += 256) {
        int oo = t / Cin, c = t % Cin;
        int o = o0 + oo;
        wsm[oo][c] = (o < Cout) ? W[(size_t)o * Cin + c] : 0.f;
    }
    __syncthreads();

    const float* Xp = X + (size_t)b * batchStride + sliceOff + n;
    float au[OT][3][2];
#pragma unroll
    for (int oo = 0; oo < OT; ++oo)
#pragma unroll
        for (int j = 0; j < 3; ++j) {
            au[oo][j][0] = 0.f; au[oo][j][1] = 0.f;
        }

    int c = 0;
    for (; c + 4 <= Cin; c += 4) {
        float2 xv[4][3];
#pragma unroll
        for (int cc = 0; cc < 4; ++cc)
#pragma unroll
            for (int j = 0; j < 3; ++j)
                xv[cc][j] = *(const float2*)(Xp + ((size_t)(c + cc) * 3 + j) * N);
#pragma unroll
        for (int oo = 0; oo < OT; ++oo) {
            float4 w4 = *(const float4*)&wsm[oo][c];
            float wv[4] = {w4.x, w4.y, w4.z, w4.w};
#pragma unroll
            for (int j = 0; j < 3; ++j) {
#pragma unroll
                for (int cc = 0; cc < 4; ++cc) {
                    au[oo][j][0] += wv[cc] * xv[cc][j].x;
                    au[oo][j][1] += wv[cc] * xv[cc][j].y;
                }
            }
        }
    }
    for (; c < Cin; ++c) {
        float2 xv[3];
#pragma unroll
        for (int j = 0; j < 3; ++j)
            xv[j] = *(const float2*)(Xp + ((size_t)c * 3 + j) * N);
#pragma unroll
        for (int oo = 0; oo < OT; ++oo) {
            float wv = wsm[oo][c];
#pragma unroll
            for (int j = 0; j < 3; ++j) {
                au[oo][j][0] += wv * xv[j].x;
                au[oo][j][1] += wv * xv[j].y;
            }
        }
    }
#pragma unroll
    for (int oo = 0; oo < OT; ++oo) {
        int o = o0 + oo;
        if (o < Cout) {
#pragma unroll
            for (int j = 0; j < 3; ++j) {
                float2 st; st.x = au[oo][j][0]; st.y = au[oo][j][1];
                *(float2*)&U[(((size_t)b * Cout + o) * 3 + j) * N + n] = st;
            }
        }
    }
}

// ---------------- layer-5 stats (deterministic): one block per channel ----------------
__global__ void k_stats_plain_det(const float* __restrict__ U, float* __restrict__ mv,
                                  int N, int Cout, int BN, float cnt) {
    int o = blockIdx.x;
    int tid = threadIdx.x;
    float s1 = 0.f, s2 = 0.f;
    for (int g = tid; g < BN; g += 256) {
        int b = g / N, n = g % N;
        const float* Ub = U + (((size_t)b * Cout + o) * 3) * N;
        float p0 = Ub[n], p1 = Ub[(size_t)N + n], p2 = Ub[(size_t)2 * N + n];
        float nm = sqrtf(p0 * p0 + p1 * p1 + p2 * p2) + EPSV;
        s1 += nm;
        s2 += nm * nm;
    }
    __shared__ float r1[256], r2[256];
    r1[tid] = s1; r2[tid] = s2;
    __syncthreads();
    for (int st = 128; st > 0; st >>= 1) {
        if (tid < st) { r1[tid] += r1[tid + st]; r2[tid] += r2[tid + st]; }
        __syncthreads();
    }
    if (tid == 0) {
        float mu = r1[0] / cnt;
        float var = r2[0] / cnt - mu * mu;
        mv[2 * o] = mu;
        mv[2 * o + 1] = rsqrtf(var + 1e-5f);
    }
}

// ---------------- layer-5 final: BN + dir leaky (1 dir channel) -> d_out ----------------
__global__ void k_final_plain(const float* __restrict__ U, const float* __restrict__ Dv,
                              const float* __restrict__ mv,
                              const float* __restrict__ gamma, const float* __restrict__ beta,
                              float* __restrict__ out, int N, int Cout) {
    int b = blockIdx.z, o = blockIdx.y, tid = threadIdx.x;
    int n = blockIdx.x * 256 + tid;
    float mu = mv[2 * o];
    float inv = mv[2 * o + 1];
    float g = gamma[o], bt = beta[o];

    const float* Ub = U + (((size_t)b * Cout + o) * 3) * N;
    float p0 = Ub[n], p1 = Ub[(size_t)N + n], p2 = Ub[(size_t)2 * N + n];
    float nm = sqrtf(p0 * p0 + p1 * p1 + p2 * p2) + EPSV;
    float nbn = (nm - mu) * inv * g + bt;
    float sc = nbn / nm;
    p0 *= sc; p1 *= sc; p2 *= sc;

    float d0 = Dv[((size_t)b * 3 + 0) * N + n];
    float d1 = Dv[((size_t)b * 3 + 1) * N + n];
    float d2 = Dv[((size_t)b * 3 + 2) * N + n];
    float dot = p0 * d0 + p1 * d1 + p2 * d2;
    float o0, o1, o2;
    if (dot >= 0.f) {
        o0 = p0; o1 = p1; o2 = p2;
    } else {
        float f = dot / (d0 * d0 + d1 * d1 + d2 * d2 + EPSV);
        o0 = NS * p0 + (1.f - NS) * (p0 - f * d0);
        o1 = NS * p1 + (1.f - NS) * (p1 - f * d1);
        o2 = NS * p2 + (1.f - NS) * (p2 - f * d2);
    }
    size_t ob = (((size_t)b * Cout + o) * 3) * N + n;
    out[ob] = o0;
    out[ob + (size_t)N] = o1;
    out[ob + (size_t)2 * N] = o2;
}

extern "C" void kernel_launch(void* const* d_in, const int* in_sizes, int n_in,
                              void* d_out, int out_size, void* d_ws, size_t ws_size,
                              hipStream_t stream) {
    (void)in_sizes; (void)n_in; (void)out_size; (void)ws_size;
    const int B = 8, N = 1024;

    const float* x = (const float*)d_in[0];
    const float* W[5]; const float* Dw[5]; const float* G[5]; const float* Bt[5];
    for (int l = 0; l < 5; ++l) {
        W[l]  = (const float*)d_in[1 + 4 * l];
        Dw[l] = (const float*)d_in[2 + 4 * l];
        G[l]  = (const float*)d_in[3 + 4 * l];
        Bt[l] = (const float*)d_in[4 + 4 * l];
    }

    float* ws = (float*)d_ws;
    size_t off = 0;
    float* xt = ws + off;     off += (size_t)B * 3 * N;
    int* idx = (int*)(ws + off); off += (size_t)B * N * KNN;
    float* catp = ws + off;   off += (size_t)B * N * CROW;
    float* catn = ws + off;   off += (size_t)B * N * CROW;
    float* Up = ws + off;     off += (size_t)B * N * 85 * 3;
    float* Vp = ws + off;     off += (size_t)B * N * 85 * 3;
    float* UDp = ws + off;    off += (size_t)B * N * 85 * 3;
    float* VDp = ws + off;    off += (size_t)B * N * 85 * 3;
    float* U5 = ws + off;     off += (size_t)B * 341 * 3 * N;
    float* d5buf = ws + off;  off += (size_t)B * 3 * N;
    float* xx = ws + off;     off += (size_t)B * N;           // 16B-aligned (all prior multiples of 4)
    float* partials = ws + off; off += (size_t)341 * SSPLIT * 2;
    float* mv = ws + off;     off += 2 * 341;

    k_transpose<<<(B * N + 255) / 256, 256, 0, stream>>>(x, xt, xx, B, N);

    const int Cin_[4]  = {1, 21, 21, 42};
    const int Cout_[4] = {21, 21, 42, 85};
    const int inOff_[4] = {-1, 0, 21, 42};
    const int outOff_[4] = {0, 21, 42, 84};
    const int Tile_[4] = {32, 32, 32, 8};   // LDS budget: L4 needs small x-tile

    const int BN = B * N;

    for (int l = 0; l < 4; ++l) {
        int C = Cin_[l], Co = Cout_[l];
        int D = C * 3;
        int CoP = (Co + 3) & ~3;
        int TILE = Tile_[l];

        // n-major source for knn
        const float* Xn; long bs, so;
        if (inOff_[l] < 0) { Xn = xt; bs = (long)3 * N; so = 0; }
        else { Xn = catn; bs = (long)CROW * N; so = (long)inOff_[l] * 3 * N; }

        // point-major source for matmul
        const float* Xp; int rs, co;
        if (inOff_[l] < 0) { Xp = x; rs = 3; co = 0; }
        else { Xp = catp; rs = CROW; co = inOff_[l] * 3; }

        // hoisted sqnorms (layer 1 fused into k_transpose)
        if (inOff_[l] >= 0)
            k_sqnorm<<<(B * N) / 256, 256, 0, stream>>>(Xn, xx, N, D, bs, so);

        dim3 gk(N / QT, B);
        k_knn<<<gk, 256, 0, stream>>>(Xn, xx, idx, N, D, bs, so);

        size_t smemB = (size_t)(4 * C * CoP + TILE * C * 3) * sizeof(float);
        k_matmul_pair_lds<<<(B * N) / TILE, 256, smemB, stream>>>(
            Xp, W[l], Dw[l], Up, Vp, UDp, VDp, C, Co, CoP, TILE, rs, co);

        dim3 gst(Co, SSPLIT);
        k_stats_edge_det<<<gst, 256, 0, stream>>>(Up, Vp, idx, partials, N, Co, BN);

        int total = BN * Co;
        k_final_edge_p<<<(total + 255) / 256, 256, 0, stream>>>(
            Up, Vp, UDp, VDp, idx, partials, G[l], Bt[l], catp,
            N, Co, outOff_[l] * 3, (float)((size_t)BN * KNN), total);

        int CC = Co * 3;
        dim3 gt(N / 32, (CC + 31) / 32, B);
        k_transpose_cat<<<gt, 256, 0, stream>>>(catp, catn, N, outOff_[l] * 3, CC);
    }

    // layer 5 (reads catn n-major)
    {
        long bs = (long)CROW * N, so = 0;
        dim3 gm5(N / 512, (341 + OT - 1) / OT, B);
        k_matmul_plain<<<gm5, 256, 0, stream>>>(catn, W[4], U5, N, 169, 341, bs, so);
        dim3 gmd(N / 512, 1, B);
        k_matmul_plain<<<gmd, 256, 0, stream>>>(catn, Dw[4], d5buf, N, 169, 1, bs, so);
        k_stats_plain_det<<<341, 256, 0, stream>>>(U5, mv, N, 341, BN, (float)BN);
        dim3 gs5(N / 256, 341, B);
        k_final_plain<<<gs5, 256, 0, stream>>>(U5, d5buf, mv, G[4], Bt[4],
                                               (float*)d_out, N, 341);
    }
}

// Round 8
// 719.817 us; speedup vs baseline: 1.0723x; 1.0538x over previous
//
#include <hip/hip_runtime.h>
#include <math.h>

#define KNN 20
#define NS 0.2f
#define EPSV 1e-6f
#define QT 4
#define OT 8
#define CROW 507   // 169*3, cat row stride (floats)
#define SSPLIT 8   // stats splits (== B; split s covers batch s exactly)

struct F3 { float x, y, z; };   // 12-byte vector load (global_load_dwordx3)

extern __shared__ __align__(16) float smem[];

// ---------------- transpose (B,N,3) -> (B,3,N) + fused sqnorm (layer-1) ----------------
__global__ void k_transpose(const float* __restrict__ x, float* __restrict__ xt,
                            float* __restrict__ xx, int B, int N) {
    int i = blockIdx.x * blockDim.x + threadIdx.x;
    if (i >= B * N) return;
    int b = i / N, n = i % N;
    const float* src = x + (size_t)(b * N + n) * 3;
    float* dst = xt + (size_t)b * 3 * N + n;
    float s0 = src[0], s1 = src[1], s2 = src[2];
    dst[0] = s0;
    dst[(size_t)N] = s1;
    dst[(size_t)2 * N] = s2;
    float s = 0.f;
    s += s0 * s0;
    s += s1 * s1;
    s += s2 * s2;
    xx[i] = s;
}

// ---------------- knn: 4 waves/block, wave-local top-k ----------------
// pd compute unchanged (bit-identical). Selection: per-lane sorted u64 keys
// (orderable-float || 1023-idx), Batcher-sorted once (explicit 63-CE network).
// Keys 0-7 stay in registers; sorted keys 8-15 spill to pd[wave]'s dead 4KB
// LDS row (wave-private, barrier-fenced). 20 extractions of {u64 max-butterfly
// + owner head-pop}; pop = 7 reg shifts + 1 ds_read_b64 refill. Head invariant
// (key[0] == list head) identical to the 16-reg version -> bit-identical idx.
__global__ void k_knn(const float* __restrict__ X, const float* __restrict__ xx,
                      int* __restrict__ idx,
                      int N, int D, long batchStride, long sliceOff) {
    int b = blockIdx.y;
    int q0 = blockIdx.x * QT;
    int tid = threadIdx.x;
    int lane = tid & 63;
    int wave = tid >> 6;

    __shared__ __align__(16) float qf[128 * QT];   // [d][q], D <= 126
    __shared__ __align__(16) float pd[QT][1024];   // N == 1024

    const float* Xb = X + (size_t)b * batchStride + sliceOff;
    const float* xxb = xx + (size_t)b * N;

    for (int t = tid; t < QT * D; t += 256) {
        int d = t >> 2, q = t & 3;
        qf[d * QT + q] = Xb[(size_t)d * N + (q0 + q)];
    }
    __syncthreads();

    float a0x = 0.f, a0y = 0.f, a0z = 0.f, a0w = 0.f;
    float a1x = 0.f, a1y = 0.f, a1z = 0.f, a1w = 0.f;
    float a2x = 0.f, a2y = 0.f, a2z = 0.f, a2w = 0.f;
    float a3x = 0.f, a3y = 0.f, a3z = 0.f, a3w = 0.f;

    const float* mbase = Xb + 4 * tid;
#pragma unroll 3
    for (int d = 0; d < D; ++d) {
        float4 xm = *(const float4*)(mbase + (size_t)d * N);
        float4 qv = *(const float4*)(qf + d * QT);
        a0x += qv.x * xm.x; a0y += qv.x * xm.y; a0z += qv.x * xm.z; a0w += qv.x * xm.w;
        a1x += qv.y * xm.x; a1y += qv.y * xm.y; a1z += qv.y * xm.z; a1w += qv.y * xm.w;
        a2x += qv.z * xm.x; a2y += qv.z * xm.y; a2z += qv.z * xm.z; a2w += qv.z * xm.w;
        a3x += qv.w * xm.x; a3y += qv.w * xm.y; a3z += qv.w * xm.z; a3w += qv.w * xm.w;
    }

    {
        float4 m2 = *(const float4*)(xxb + 4 * tid);   // ||x_m||^2, 4 m's
        float4 qn = *(const float4*)(xxb + q0);        // ||x_q||^2, 4 q's
        float4 v;
        v.x = 2.f * a0x - qn.x - m2.x; v.y = 2.f * a0y - qn.x - m2.y;
        v.z = 2.f * a0z - qn.x - m2.z; v.w = 2.f * a0w - qn.x - m2.w;
        *(float4*)&pd[0][4 * tid] = v;
        v.x = 2.f * a1x - qn.y - m2.x; v.y = 2.f * a1y - qn.y - m2.y;
        v.z = 2.f * a1z - qn.y - m2.z; v.w = 2.f * a1w - qn.y - m2.w;
        *(float4*)&pd[1][4 * tid] = v;
        v.x = 2.f * a2x - qn.z - m2.x; v.y = 2.f * a2y - qn.z - m2.y;
        v.z = 2.f * a2z - qn.z - m2.z; v.w = 2.f * a2w - qn.z - m2.w;
        *(float4*)&pd[2][4 * tid] = v;
        v.x = 2.f * a3x - qn.w - m2.x; v.y = 2.f * a3y - qn.w - m2.y;
        v.z = 2.f * a3z - qn.w - m2.z; v.w = 2.f * a3w - qn.w - m2.w;
        *(float4*)&pd[3][4 * tid] = v;
    }
    __syncthreads();

    // ---- build sortable keys: hi = orderable(float bits), lo = 1023 - idx ----
    unsigned long long key[16];
#pragma unroll
    for (int t = 0; t < 16; ++t) {
        unsigned u = __float_as_uint(pd[wave][t * 64 + lane]);
        u ^= (unsigned)((int)u >> 31) | 0x80000000u;
        unsigned lo = (unsigned)(1023 - t * 64) - (unsigned)lane;
        key[t] = ((unsigned long long)u << 32) | (unsigned long long)lo;
    }

    // ---- per-lane descending sort: explicit Batcher odd-even mergesort n=16 ----
#define CE(a, b)                                        \
    {                                                   \
        unsigned long long ka = key[a], kb = key[b];    \
        bool sw = ka < kb;                              \
        key[a] = sw ? kb : ka;                          \
        key[b] = sw ? ka : kb;                          \
    }
    CE(0,1) CE(2,3) CE(4,5) CE(6,7) CE(8,9) CE(10,11) CE(12,13) CE(14,15)
    CE(0,2) CE(1,3) CE(4,6) CE(5,7) CE(8,10) CE(9,11) CE(12,14) CE(13,15)
    CE(1,2) CE(5,6) CE(9,10) CE(13,14)
    CE(0,4) CE(1,5) CE(2,6) CE(3,7) CE(8,12) CE(9,13) CE(10,14) CE(11,15)
    CE(2,4) CE(3,5) CE(10,12) CE(11,13)
    CE(1,2) CE(3,4) CE(5,6) CE(9,10) CE(11,12) CE(13,14)
    CE(0,8) CE(1,9) CE(2,10) CE(3,11) CE(4,12) CE(5,13) CE(6,14) CE(7,15)
    CE(4,8) CE(5,9) CE(6,10) CE(7,11)
    CE(2,4) CE(3,5) CE(6,8) CE(7,9) CE(10,12) CE(11,13)
    CE(1,2) CE(3,4) CE(5,6) CE(7,8) CE(9,10) CE(11,12) CE(13,14)
#undef CE

    // ---- spill keys 8..15 to pd[wave]'s row (dead after key build) ----
    // barrier fences the float reads above vs u64 writes below (TBAA safety)
    __syncthreads();
    unsigned long long* kl = (unsigned long long*)&pd[wave][0];  // 512 u64, wave-private
#pragma unroll
    for (int t = 8; t < 16; ++t) kl[(t - 8) * 64 + lane] = key[t];
    int nspill = 0;

    // ---- 20 extractions: u64 max-butterfly + owner head-pop (LDS refill) ----
    long outBase = ((long)b * N + q0 + wave) * KNN;
    for (int it = 0; it < KNN; ++it) {
        unsigned long long bk = key[0];
#pragma unroll
        for (int off = 32; off >= 1; off >>= 1) {
            unsigned long long ok = __shfl_xor(bk, off, 64);
            if (ok > bk) bk = ok;
        }
        int bi = 1023 - (int)(bk & 1023u);
        if (lane == 0) idx[outBase + it] = bi;
        if ((bi & 63) == lane) {
            key[0] = key[1]; key[1] = key[2]; key[2] = key[3]; key[3] = key[4];
            key[4] = key[5]; key[5] = key[6]; key[6] = key[7];
            int sidx = nspill < 8 ? nspill : 7;            // clamp: stay in wave's 4KB row
            unsigned long long nv = kl[sidx * 64 + lane];
            key[7] = (nspill < 8) ? nv : 0ull;             // sentinel below all real keys
            nspill++;
        }
    }
}

// ---------------- LDS-staged point-major pair matmul ----------------
__global__ void k_matmul_pair_lds(const float* __restrict__ X, const float* __restrict__ W,
                                  const float* __restrict__ Dw,
                                  float* __restrict__ U, float* __restrict__ V,
                                  float* __restrict__ UD, float* __restrict__ VD,
                                  int C, int Co, int CoP, int TILE,
                                  int rowStride, int colOff) {
    const int CP = C * CoP;
    float* wts = smem;            // 4*CP: [WA | WB-WA | DA | DB-DA], each [c][o]
    float* xs = smem + 4 * CP;    // TILE * C * 3

    int tid = threadIdx.x;
    int bn0 = blockIdx.x * TILE;  // flattened b*N+n base
    int C3 = C * 3;

    // zero padded o-lanes
    int npad = CoP - Co;
    if (npad) {
        for (int t = tid; t < 4 * C * npad; t += 256) {
            int q = t / npad, oo = Co + t % npad;
            int mat = q / C, c = q % C;
            wts[mat * CP + c * CoP + oo] = 0.f;
        }
    }
    // stage raw weights (coalesced global reads, LDS transpose writes)
    int twoCC = 2 * C * Co;
    for (int t = tid; t < twoCC; t += 256) {
        int o = t / (2 * C), c = t % (2 * C);
        float w = W[t], dw = Dw[t];
        if (c < C) {
            wts[c * CoP + o] = w;
            wts[2 * CP + c * CoP + o] = dw;
        } else {
            wts[CP + (c - C) * CoP + o] = w;
            wts[3 * CP + (c - C) * CoP + o] = dw;
        }
    }
    // stage point rows (coalesced)
    for (int t = tid; t < TILE * C3; t += 256) {
        int p = t / C3, cc = t % C3;
        xs[t] = X[(size_t)(bn0 + p) * rowStride + colOff + cc];
    }
    __syncthreads();
    // WB -= WA, DB -= DA in place
    for (int t = tid; t < CP; t += 256) {
        wts[CP + t] -= wts[t];
        wts[3 * CP + t] -= wts[2 * CP + t];
    }
    __syncthreads();

    int GPP = CoP >> 2;
    int items = TILE * GPP;
    for (int e = tid; e < items; e += 256) {
        int p = e / GPP, og = e - p * GPP;
        int o0 = og * 4;
        const float* xr = xs + p * C3;

        float aU[4][3], aV[4][3], aDu[4][3], aDv[4][3];
#pragma unroll
        for (int i = 0; i < 4; ++i)
#pragma unroll
            for (int j = 0; j < 3; ++j) {
                aU[i][j] = 0.f; aV[i][j] = 0.f; aDu[i][j] = 0.f; aDv[i][j] = 0.f;
            }

        for (int c = 0; c < C; ++c) {
            float x0 = xr[c * 3], x1 = xr[c * 3 + 1], x2 = xr[c * 3 + 2];
            const float* wp = wts + c * CoP + o0;
            float4 wa4 = *(const float4*)(wp);
            float4 wb4 = *(const float4*)(wp + CP);
            float4 da4 = *(const float4*)(wp + 2 * CP);
            float4 db4 = *(const float4*)(wp + 3 * CP);
            float wav[4] = {wa4.x, wa4.y, wa4.z, wa4.w};
            float wbv[4] = {wb4.x, wb4.y, wb4.z, wb4.w};
            float dav[4] = {da4.x, da4.y, da4.z, da4.w};
            float dbv[4] = {db4.x, db4.y, db4.z, db4.w};
#pragma unroll
            for (int i = 0; i < 4; ++i) {
                aU[i][0] += wav[i] * x0; aU[i][1] += wav[i] * x1; aU[i][2] += wav[i] * x2;
                aV[i][0] += wbv[i] * x0; aV[i][1] += wbv[i] * x1; aV[i][2] += wbv[i] * x2;
                aDu[i][0] += dav[i] * x0; aDu[i][1] += dav[i] * x1; aDu[i][2] += dav[i] * x2;
                aDv[i][0] += dbv[i] * x0; aDv[i][1] += dbv[i] * x1; aDv[i][2] += dbv[i] * x2;
            }
        }

        size_t base = ((size_t)(bn0 + p) * Co + o0) * 3;
#pragma unroll
        for (int i = 0; i < 4; ++i) {
            int o = o0 + i;
            if (o < Co) {
                size_t off = base + (size_t)i * 3;
                U[off] = aU[i][0]; U[off + 1] = aU[i][1]; U[off + 2] = aU[i][2];
                V[off] = aV[i][0]; V[off + 1] = aV[i][1]; V[off + 2] = aV[i][2];
                UD[off] = aDu[i][0]; UD[off + 1] = aDu[i][1]; UD[off + 2] = aDu[i][2];
                VD[off] = aDv[i][0]; VD[off + 1] = aDv[i][1]; VD[off + 2] = aDv[i][2];
            }
        }
    }
}

// ---------------- BN stats stage A (deterministic, R5 order + LDS staging) ----------------
__global__ void k_stats_edge_det(const float* __restrict__ U, const float* __restrict__ V,
                                 const int* __restrict__ idx, float* __restrict__ partials,
                                 int N, int Co, int BN) {
    int o = blockIdx.x;
    int s = blockIdx.y;
    int tid = threadIdx.x;
    int P = BN / SSPLIT;      // == N == 1024
    int g0 = s * P;

    __shared__ float Ush[3072];   // N * 3 (channel-o vectors for batch s)
    __shared__ float r1[256], r2[256];

    for (int t = tid; t < P; t += 256) {
        F3 u3 = *(const F3*)(U + ((size_t)(g0 + t) * Co + o) * 3);
        Ush[t * 3 + 0] = u3.x;
        Ush[t * 3 + 1] = u3.y;
        Ush[t * 3 + 2] = u3.z;
    }
    __syncthreads();

    float s1 = 0.f, s2 = 0.f;
    for (int pl = tid; pl < P; pl += 256) {
        int g = g0 + pl;                       // flattened b*N+n
        F3 v3 = *(const F3*)(V + ((size_t)g * Co + o) * 3);
        float v0 = v3.x, v1 = v3.y, v2 = v3.z;
        const int* ip = idx + (size_t)g * KNN;
        for (int kk = 0; kk < KNN; ++kk) {
            const float* Ur = Ush + ip[kk] * 3;   // idx is batch-local
            float p0 = Ur[0] + v0;
            float p1 = Ur[1] + v1;
            float p2 = Ur[2] + v2;
            float nm = sqrtf(p0 * p0 + p1 * p1 + p2 * p2) + EPSV;
            s1 += nm;
            s2 += nm * nm;
        }
    }
    r1[tid] = s1; r2[tid] = s2;
    __syncthreads();
    for (int st = 128; st > 0; st >>= 1) {
        if (tid < st) { r1[tid] += r1[tid + st]; r2[tid] += r2[tid + st]; }
        __syncthreads();
    }
    if (tid == 0) {
        partials[(o * SSPLIT + s) * 2] = r1[0];
        partials[(o * SSPLIT + s) * 2 + 1] = r2[0];
    }
}

// ---------------- BN + dir leaky + mean-pool (fused stage-B), thread per (b,n,o) ----------------
__global__ void k_final_edge_p(const float* __restrict__ U, const float* __restrict__ V,
                               const float* __restrict__ UD, const float* __restrict__ VD,
                               const int* __restrict__ idx, const float* __restrict__ partials,
                               const float* __restrict__ gamma, const float* __restrict__ beta,
                               float* __restrict__ catp,
                               int N, int Co, int colOff, float cnt, int total) {
    int g = blockIdx.x * 256 + threadIdx.x;
    if (g >= total) return;
    int o = g % Co;
    int r = g / Co;
    int n = r % N;
    int b = r / N;

    float s1 = 0.f, s2 = 0.f;
    for (int s = 0; s < SSPLIT; ++s) {
        s1 += partials[(o * SSPLIT + s) * 2];
        s2 += partials[(o * SSPLIT + s) * 2 + 1];
    }
    float mu = s1 / cnt;
    float var = s2 / cnt - mu * mu;
    float inv = rsqrtf(var + 1e-5f);
    float gmm = gamma[o], bt = beta[o];

    size_t ctr = ((size_t)(b * N + n) * Co + o) * 3;
    F3 vc = *(const F3*)(V + ctr);
    F3 wc = *(const F3*)(VD + ctr);
    float v0 = vc.x, v1 = vc.y, v2 = vc.z;
    float w0 = wc.x, w1 = wc.y, w2 = wc.z;
    const int* ip = idx + ((size_t)b * N + n) * KNN;

    float a0 = 0.f, a1 = 0.f, a2 = 0.f;
    for (int kk = 0; kk < KNN; ++kk) {
        int m = ip[kk];
        size_t nb = ((size_t)(b * N + m) * Co + o) * 3;
        F3 un = *(const F3*)(U + nb);
        F3 dn = *(const F3*)(UD + nb);
        float p0 = un.x + v0;
        float p1 = un.y + v1;
        float p2 = un.z + v2;
        float nm = sqrtf(p0 * p0 + p1 * p1 + p2 * p2) + EPSV;
        float nbn = (nm - mu) * inv * gmm + bt;
        float sc = nbn / nm;
        p0 *= sc; p1 *= sc; p2 *= sc;
        float d0 = dn.x + w0;
        float d1 = dn.y + w1;
        float d2 = dn.z + w2;
        float dot = p0 * d0 + p1 * d1 + p2 * d2;
        if (dot >= 0.f) {
            a0 += p0; a1 += p1; a2 += p2;
        } else {
            float f = dot / (d0 * d0 + d1 * d1 + d2 * d2 + EPSV);
            a0 += NS * p0 + (1.f - NS) * (p0 - f * d0);
            a1 += NS * p1 + (1.f - NS) * (p1 - f * d1);
            a2 += NS * p2 + (1.f - NS) * (p2 - f * d2);
        }
    }
    const float invk = 1.f / (float)KNN;
    float* outp = catp + (size_t)(b * N + n) * CROW + colOff + o * 3;
    outp[0] = a0 * invk;
    outp[1] = a1 * invk;
    outp[2] = a2 * invk;
}

// ---------------- cat_p slice -> cat_n slice (LDS tiled transpose) + fused next-layer sqnorm ----
// Extra blockIdx.y slice (when doSq) computes xx for the NEXT layer from catp
// (row-major; ascending-c accumulation == old k_sqnorm's ascending-d chain ->
// bit-identical). Legal: this layer's output slice [c0, c0+CC) IS the next
// layer's knn input slice, and catp is complete before this launch.
__global__ void k_transpose_cat(const float* __restrict__ catp, float* __restrict__ catn,
                                int N, int c0, int CC,
                                float* __restrict__ xx, int doSq) {
    int ytiles = (CC + 31) >> 5;
    if (doSq && (int)blockIdx.y == ytiles) {
        if (blockIdx.z != 0) return;
        int i = blockIdx.x * 256 + threadIdx.x;     // 32 blocks x 256 = 8192 = B*N
        const float* row = catp + (size_t)i * CROW + c0;
        float s = 0.f;
        for (int c = 0; c < CC; ++c) {
            float v = row[c];
            s += v * v;
        }
        xx[i] = s;
        return;
    }

    __shared__ float tile[32][33];
    int b = blockIdx.z;
    int n0 = blockIdx.x * 32;
    int cb = blockIdx.y * 32;
    int tid = threadIdx.x;
    int tx = tid & 31, ty = tid >> 5;   // 32 x 8

#pragma unroll
    for (int rr = 0; rr < 4; ++rr) {
        int nl = ty + rr * 8;
        int c = cb + tx;
        if (c < CC)
            tile[nl][tx] = catp[(size_t)(b * N + n0 + nl) * CROW + c0 + c];
    }
    __syncthreads();
#pragma unroll
    for (int rr = 0; rr < 4; ++rr) {
        int cl = ty + rr * 8;
        int c = cb + cl;
        if (c < CC)
            catn[(size_t)b * CROW * N + (size_t)(c0 + c) * N + n0 + tx] = tile[tx][cl];
    }
}

// ---------------- plain matmul (layer 5, n-major): U = W*x, j-fused + 2-n tile ----------
// W and Dw launches merged: last blockIdx.y tile runs the Dw (Cout=1) path —
// identical body, o0=0, output to Ud. Both paths bit-identical to the split
// launches (same per-(o,j,n) ascending-c chains).
__global__ void k_matmul_plain(const float* __restrict__ X, const float* __restrict__ W,
                               const float* __restrict__ Dw,
                               float* __restrict__ U, float* __restrict__ Ud,
                               int N, int Cin, int Cout, long batchStride, long sliceOff) {
    int ot = blockIdx.y;
    int b = blockIdx.z;
    int tid = threadIdx.x;
    int n = blockIdx.x * 512 + 2 * tid;

    const float* Wp; float* Up; int CoutE; int o0;
    if (ot == (int)gridDim.y - 1) {   // Dw path
        Wp = Dw; Up = Ud; CoutE = 1; o0 = 0;
    } else {
        Wp = W; Up = U; CoutE = Cout; o0 = ot * OT;
    }

    __shared__ __align__(16) float wsm[OT][176];  // Cin <= 169; stride 176 keeps rows 16B-aligned
    for (int t = tid; t < OT * Cin; t += 256) {
        int oo = t / Cin, c = t % Cin;
        int o = o0 + oo;
        wsm[oo][c] = (o < CoutE) ? Wp[(size_t)o * Cin + c] : 0.f;
    }
    __syncthreads();

    const float* Xp = X + (size_t)b * batchStride + sliceOff + n;
    float au[OT][3][2];
#pragma unroll
    for (int oo = 0; oo < OT; ++oo)
#pragma unroll
        for (int j = 0; j < 3; ++j) {
            au[oo][j][0] = 0.f; au[oo][j][1] = 0.f;
        }

    int c = 0;
    for (; c + 4 <= Cin; c += 4) {
        float2 xv[4][3];
#pragma unroll
        for (int cc = 0; cc < 4; ++cc)
#pragma unroll
            for (int j = 0; j < 3; ++j)
                xv[cc][j] = *(const float2*)(Xp + ((size_t)(c + cc) * 3 + j) * N);
#pragma unroll
        for (int oo = 0; oo < OT; ++oo) {
            float4 w4 = *(const float4*)&wsm[oo][c];
            float wv[4] = {w4.x, w4.y, w4.z, w4.w};
#pragma unroll
            for (int j = 0; j < 3; ++j) {
#pragma unroll
                for (int cc = 0; cc < 4; ++cc) {
                    au[oo][j][0] += wv[cc] * xv[cc][j].x;
                    au[oo][j][1] += wv[cc] * xv[cc][j].y;
                }
            }
        }
    }
    for (; c < Cin; ++c) {
        float2 xv[3];
#pragma unroll
        for (int j = 0; j < 3; ++j)
            xv[j] = *(const float2*)(Xp + ((size_t)c * 3 + j) * N);
#pragma unroll
        for (int oo = 0; oo < OT; ++oo) {
            float wv = wsm[oo][c];
#pragma unroll
            for (int j = 0; j < 3; ++j) {
                au[oo][j][0] += wv * xv[j].x;
                au[oo][j][1] += wv * xv[j].y;
            }
        }
    }
#pragma unroll
    for (int oo = 0; oo < OT; ++oo) {
        int o = o0 + oo;
        if (o < CoutE) {
#pragma unroll
            for (int j = 0; j < 3; ++j) {
                float2 st; st.x = au[oo][j][0]; st.y = au[oo][j][1];
                *(float2*)&Up[(((size_t)b * CoutE + o) * 3 + j) * N + n] = st;
            }
        }
    }
}

// ---------------- layer-5 stats (deterministic): one block per channel ----------------
__global__ void k_stats_plain_det(const float* __restrict__ U, float* __restrict__ mv,
                                  int N, int Cout, int BN, float cnt) {
    int o = blockIdx.x;
    int tid = threadIdx.x;
    float s1 = 0.f, s2 = 0.f;
    for (int g = tid; g < BN; g += 256) {
        int b = g / N, n = g % N;
        const float* Ub = U + (((size_t)b * Cout + o) * 3) * N;
        float p0 = Ub[n], p1 = Ub[(size_t)N + n], p2 = Ub[(size_t)2 * N + n];
        float nm = sqrtf(p0 * p0 + p1 * p1 + p2 * p2) + EPSV;
        s1 += nm;
        s2 += nm * nm;
    }
    __shared__ float r1[256], r2[256];
    r1[tid] = s1; r2[tid] = s2;
    __syncthreads();
    for (int st = 128; st > 0; st >>= 1) {
        if (tid < st) { r1[tid] += r1[tid + st]; r2[tid] += r2[tid + st]; }
        __syncthreads();
    }
    if (tid == 0) {
        float mu = r1[0] / cnt;
        float var = r2[0] / cnt - mu * mu;
        mv[2 * o] = mu;
        mv[2 * o + 1] = rsqrtf(var + 1e-5f);
    }
}

// ---------------- layer-5 final: BN + dir leaky (1 dir channel) -> d_out ----------------
__global__ void k_final_plain(const float* __restrict__ U, const float* __restrict__ Dv,
                              const float* __restrict__ mv,
                              const float* __restrict__ gamma, const float* __restrict__ beta,
                              float* __restrict__ out, int N, int Cout) {
    int b = blockIdx.z, o = blockIdx.y, tid = threadIdx.x;
    int n = blockIdx.x * 256 + tid;
    float mu = mv[2 * o];
    float inv = mv[2 * o + 1];
    float g = gamma[o], bt = beta[o];

    const float* Ub = U + (((size_t)b * Cout + o) * 3) * N;
    float p0 = Ub[n], p1 = Ub[(size_t)N + n], p2 = Ub[(size_t)2 * N + n];
    float nm = sqrtf(p0 * p0 + p1 * p1 + p2 * p2) + EPSV;
    float nbn = (nm - mu) * inv * g + bt;
    float sc = nbn / nm;
    p0 *= sc; p1 *= sc; p2 *= sc;

    float d0 = Dv[((size_t)b * 3 + 0) * N + n];
    float d1 = Dv[((size_t)b * 3 + 1) * N + n];
    float d2 = Dv[((size_t)b * 3 + 2) * N + n];
    float dot = p0 * d0 + p1 * d1 + p2 * d2;
    float o0, o1, o2;
    if (dot >= 0.f) {
        o0 = p0; o1 = p1; o2 = p2;
    } else {
        float f = dot / (d0 * d0 + d1 * d1 + d2 * d2 + EPSV);
        o0 = NS * p0 + (1.f - NS) * (p0 - f * d0);
        o1 = NS * p1 + (1.f - NS) * (p1 - f * d1);
        o2 = NS * p2 + (1.f - NS) * (p2 - f * d2);
    }
    size_t ob = (((size_t)b * Cout + o) * 3) * N + n;
    out[ob] = o0;
    out[ob + (size_t)N] = o1;
    out[ob + (size_t)2 * N] = o2;
}

extern "C" void kernel_launch(void* const* d_in, const int* in_sizes, int n_in,
                              void* d_out, int out_size, void* d_ws, size_t ws_size,
                              hipStream_t stream) {
    (void)in_sizes; (void)n_in; (void)out_size; (void)ws_size;
    const int B = 8, N = 1024;

    const float* x = (const float*)d_in[0];
    const float* W[5]; const float* Dw[5]; const float* G[5]; const float* Bt[5];
    for (int l = 0; l < 5; ++l) {
        W[l]  = (const float*)d_in[1 + 4 * l];
        Dw[l] = (const float*)d_in[2 + 4 * l];
        G[l]  = (const float*)d_in[3 + 4 * l];
        Bt[l] = (const float*)d_in[4 + 4 * l];
    }

    float* ws = (float*)d_ws;
    size_t off = 0;
    float* xt = ws + off;     off += (size_t)B * 3 * N;
    int* idx = (int*)(ws + off); off += (size_t)B * N * KNN;
    float* catp = ws + off;   off += (size_t)B * N * CROW;
    float* catn = ws + off;   off += (size_t)B * N * CROW;
    float* Up = ws + off;     off += (size_t)B * N * 85 * 3;
    float* Vp = ws + off;     off += (size_t)B * N * 85 * 3;
    float* UDp = ws + off;    off += (size_t)B * N * 85 * 3;
    float* VDp = ws + off;    off += (size_t)B * N * 85 * 3;
    float* U5 = ws + off;     off += (size_t)B * 341 * 3 * N;
    float* d5buf = ws + off;  off += (size_t)B * 3 * N;
    float* xx = ws + off;     off += (size_t)B * N;           // 16B-aligned (all prior multiples of 4)
    float* partials = ws + off; off += (size_t)341 * SSPLIT * 2;
    float* mv = ws + off;     off += 2 * 341;

    k_transpose<<<(B * N + 255) / 256, 256, 0, stream>>>(x, xt, xx, B, N);

    const int Cin_[4]  = {1, 21, 21, 42};
    const int Cout_[4] = {21, 21, 42, 85};
    const int inOff_[4] = {-1, 0, 21, 42};
    const int outOff_[4] = {0, 21, 42, 84};
    const int Tile_[4] = {32, 32, 32, 8};   // LDS budget: L4 needs small x-tile

    const int BN = B * N;

    for (int l = 0; l < 4; ++l) {
        int C = Cin_[l], Co = Cout_[l];
        int D = C * 3;
        int CoP = (Co + 3) & ~3;
        int TILE = Tile_[l];

        // n-major source for knn
        const float* Xn; long bs, so;
        if (inOff_[l] < 0) { Xn = xt; bs = (long)3 * N; so = 0; }
        else { Xn = catn; bs = (long)CROW * N; so = (long)inOff_[l] * 3 * N; }

        // point-major source for matmul
        const float* Xp; int rs, co;
        if (inOff_[l] < 0) { Xp = x; rs = 3; co = 0; }
        else { Xp = catp; rs = CROW; co = inOff_[l] * 3; }

        // xx for this layer was produced by k_transpose (l=0) or the previous
        // layer's fused k_transpose_cat (l>=1)
        dim3 gk(N / QT, B);
        k_knn<<<gk, 256, 0, stream>>>(Xn, xx, idx, N, D, bs, so);

        size_t smemB = (size_t)(4 * C * CoP + TILE * C * 3) * sizeof(float);
        k_matmul_pair_lds<<<(B * N) / TILE, 256, smemB, stream>>>(
            Xp, W[l], Dw[l], Up, Vp, UDp, VDp, C, Co, CoP, TILE, rs, co);

        dim3 gst(Co, SSPLIT);
        k_stats_edge_det<<<gst, 256, 0, stream>>>(Up, Vp, idx, partials, N, Co, BN);

        int total = BN * Co;
        k_final_edge_p<<<(total + 255) / 256, 256, 0, stream>>>(
            Up, Vp, UDp, VDp, idx, partials, G[l], Bt[l], catp,
            N, Co, outOff_[l] * 3, (float)((size_t)BN * KNN), total);

        int CC = Co * 3;
        int doSq = (l < 3) ? 1 : 0;   // layers 0-2 produce xx for the next layer
        dim3 gt(N / 32, (CC + 31) / 32 + doSq, B);
        k_transpose_cat<<<gt, 256, 0, stream>>>(catp, catn, N, outOff_[l] * 3, CC, xx, doSq);
    }

    // layer 5 (reads catn n-major); W and Dw matmuls merged into one launch
    {
        long bs = (long)CROW * N, so = 0;
        dim3 gm5(N / 512, (341 + OT - 1) / OT + 1, B);   // +1: Dw tile
        k_matmul_plain<<<gm5, 256, 0, stream>>>(catn, W[4], Dw[4], U5, d5buf,
                                                N, 169, 341, bs, so);
        k_stats_plain_det<<<341, 256, 0, stream>>>(U5, mv, N, 341, BN, (float)BN);
        dim3 gs5(N / 256, 341, B);
        k_final_plain<<<gs5, 256, 0, stream>>>(U5, d5buf, mv, G[4], Bt[4],
                                               (float*)d_out, N, 341);
    }
}

// Round 9
// 676.705 us; speedup vs baseline: 1.1406x; 1.0637x over previous
//
#include <hip/hip_runtime.h>
#include <math.h>

#define KNN 20
#define NS 0.2f
#define EPSV 1e-6f
#define QT 4
#define OT 8
#define TN 8       // n-tile of k_final_fused
#define CROW 507   // 169*3, cat row stride (floats)
#define SSPLIT 8   // stats splits (== B; split s covers batch s exactly)

struct F3 { float x, y, z; };   // 12-byte vector load (global_load_dwordx3)

extern __shared__ __align__(16) float smem[];

// ---------------- transpose (B,N,3) -> (B,3,N) + fused sqnorm (layer-1) ----------------
__global__ void k_transpose(const float* __restrict__ x, float* __restrict__ xt,
                            float* __restrict__ xx, int B, int N) {
    int i = blockIdx.x * blockDim.x + threadIdx.x;
    if (i >= B * N) return;
    int b = i / N, n = i % N;
    const float* src = x + (size_t)(b * N + n) * 3;
    float* dst = xt + (size_t)b * 3 * N + n;
    float s0 = src[0], s1 = src[1], s2 = src[2];
    dst[0] = s0;
    dst[(size_t)N] = s1;
    dst[(size_t)2 * N] = s2;
    float s = 0.f;
    s += s0 * s0;
    s += s1 * s1;
    s += s2 * s2;
    xx[i] = s;
}

// ---------------- knn: 4 waves/block, wave-local top-k (R8 version, 73 us) ----------------
__global__ void k_knn(const float* __restrict__ X, const float* __restrict__ xx,
                      int* __restrict__ idx,
                      int N, int D, long batchStride, long sliceOff) {
    int b = blockIdx.y;
    int q0 = blockIdx.x * QT;
    int tid = threadIdx.x;
    int lane = tid & 63;
    int wave = tid >> 6;

    __shared__ __align__(16) float qf[128 * QT];   // [d][q], D <= 126
    __shared__ __align__(16) float pd[QT][1024];   // N == 1024

    const float* Xb = X + (size_t)b * batchStride + sliceOff;
    const float* xxb = xx + (size_t)b * N;

    for (int t = tid; t < QT * D; t += 256) {
        int d = t >> 2, q = t & 3;
        qf[d * QT + q] = Xb[(size_t)d * N + (q0 + q)];
    }
    __syncthreads();

    float a0x = 0.f, a0y = 0.f, a0z = 0.f, a0w = 0.f;
    float a1x = 0.f, a1y = 0.f, a1z = 0.f, a1w = 0.f;
    float a2x = 0.f, a2y = 0.f, a2z = 0.f, a2w = 0.f;
    float a3x = 0.f, a3y = 0.f, a3z = 0.f, a3w = 0.f;

    const float* mbase = Xb + 4 * tid;
#pragma unroll 3
    for (int d = 0; d < D; ++d) {
        float4 xm = *(const float4*)(mbase + (size_t)d * N);
        float4 qv = *(const float4*)(qf + d * QT);
        a0x += qv.x * xm.x; a0y += qv.x * xm.y; a0z += qv.x * xm.z; a0w += qv.x * xm.w;
        a1x += qv.y * xm.x; a1y += qv.y * xm.y; a1z += qv.y * xm.z; a1w += qv.y * xm.w;
        a2x += qv.z * xm.x; a2y += qv.z * xm.y; a2z += qv.z * xm.z; a2w += qv.z * xm.w;
        a3x += qv.w * xm.x; a3y += qv.w * xm.y; a3z += qv.w * xm.z; a3w += qv.w * xm.w;
    }

    {
        float4 m2 = *(const float4*)(xxb + 4 * tid);   // ||x_m||^2, 4 m's
        float4 qn = *(const float4*)(xxb + q0);        // ||x_q||^2, 4 q's
        float4 v;
        v.x = 2.f * a0x - qn.x - m2.x; v.y = 2.f * a0y - qn.x - m2.y;
        v.z = 2.f * a0z - qn.x - m2.z; v.w = 2.f * a0w - qn.x - m2.w;
        *(float4*)&pd[0][4 * tid] = v;
        v.x = 2.f * a1x - qn.y - m2.x; v.y = 2.f * a1y - qn.y - m2.y;
        v.z = 2.f * a1z - qn.y - m2.z; v.w = 2.f * a1w - qn.y - m2.w;
        *(float4*)&pd[1][4 * tid] = v;
        v.x = 2.f * a2x - qn.z - m2.x; v.y = 2.f * a2y - qn.z - m2.y;
        v.z = 2.f * a2z - qn.z - m2.z; v.w = 2.f * a2w - qn.z - m2.w;
        *(float4*)&pd[2][4 * tid] = v;
        v.x = 2.f * a3x - qn.w - m2.x; v.y = 2.f * a3y - qn.w - m2.y;
        v.z = 2.f * a3z - qn.w - m2.z; v.w = 2.f * a3w - qn.w - m2.w;
        *(float4*)&pd[3][4 * tid] = v;
    }
    __syncthreads();

    // ---- build sortable keys: hi = orderable(float bits), lo = 1023 - idx ----
    unsigned long long key[16];
#pragma unroll
    for (int t = 0; t < 16; ++t) {
        unsigned u = __float_as_uint(pd[wave][t * 64 + lane]);
        u ^= (unsigned)((int)u >> 31) | 0x80000000u;
        unsigned lo = (unsigned)(1023 - t * 64) - (unsigned)lane;
        key[t] = ((unsigned long long)u << 32) | (unsigned long long)lo;
    }

    // ---- per-lane descending sort: explicit Batcher odd-even mergesort n=16 ----
#define CE(a, b)                                        \
    {                                                   \
        unsigned long long ka = key[a], kb = key[b];    \
        bool sw = ka < kb;                              \
        key[a] = sw ? kb : ka;                          \
        key[b] = sw ? ka : kb;                          \
    }
    CE(0,1) CE(2,3) CE(4,5) CE(6,7) CE(8,9) CE(10,11) CE(12,13) CE(14,15)
    CE(0,2) CE(1,3) CE(4,6) CE(5,7) CE(8,10) CE(9,11) CE(12,14) CE(13,15)
    CE(1,2) CE(5,6) CE(9,10) CE(13,14)
    CE(0,4) CE(1,5) CE(2,6) CE(3,7) CE(8,12) CE(9,13) CE(10,14) CE(11,15)
    CE(2,4) CE(3,5) CE(10,12) CE(11,13)
    CE(1,2) CE(3,4) CE(5,6) CE(9,10) CE(11,12) CE(13,14)
    CE(0,8) CE(1,9) CE(2,10) CE(3,11) CE(4,12) CE(5,13) CE(6,14) CE(7,15)
    CE(4,8) CE(5,9) CE(6,10) CE(7,11)
    CE(2,4) CE(3,5) CE(6,8) CE(7,9) CE(10,12) CE(11,13)
    CE(1,2) CE(3,4) CE(5,6) CE(7,8) CE(9,10) CE(11,12) CE(13,14)
#undef CE

    // ---- spill keys 8..15 to pd[wave]'s row (dead after key build) ----
    __syncthreads();
    unsigned long long* kl = (unsigned long long*)&pd[wave][0];  // 512 u64, wave-private
#pragma unroll
    for (int t = 8; t < 16; ++t) kl[(t - 8) * 64 + lane] = key[t];
    int nspill = 0;

    // ---- 20 extractions: u64 max-butterfly + owner head-pop (LDS refill) ----
    long outBase = ((long)b * N + q0 + wave) * KNN;
    for (int it = 0; it < KNN; ++it) {
        unsigned long long bk = key[0];
#pragma unroll
        for (int off = 32; off >= 1; off >>= 1) {
            unsigned long long ok = __shfl_xor(bk, off, 64);
            if (ok > bk) bk = ok;
        }
        int bi = 1023 - (int)(bk & 1023u);
        if (lane == 0) idx[outBase + it] = bi;
        if ((bi & 63) == lane) {
            key[0] = key[1]; key[1] = key[2]; key[2] = key[3]; key[3] = key[4];
            key[4] = key[5]; key[5] = key[6]; key[6] = key[7];
            int sidx = nspill < 8 ? nspill : 7;            // clamp: stay in wave's 4KB row
            unsigned long long nv = kl[sidx * 64 + lane];
            key[7] = (nspill < 8) ? nv : 0ull;             // sentinel below all real keys
            nspill++;
        }
    }
}

// ---------------- LDS-staged point-major pair matmul ----------------
__global__ void k_matmul_pair_lds(const float* __restrict__ X, const float* __restrict__ W,
                                  const float* __restrict__ Dw,
                                  float* __restrict__ U, float* __restrict__ V,
                                  float* __restrict__ UD, float* __restrict__ VD,
                                  int C, int Co, int CoP, int TILE,
                                  int rowStride, int colOff) {
    const int CP = C * CoP;
    float* wts = smem;            // 4*CP: [WA | WB-WA | DA | DB-DA], each [c][o]
    float* xs = smem + 4 * CP;    // TILE * C * 3

    int tid = threadIdx.x;
    int bn0 = blockIdx.x * TILE;  // flattened b*N+n base
    int C3 = C * 3;

    // zero padded o-lanes
    int npad = CoP - Co;
    if (npad) {
        for (int t = tid; t < 4 * C * npad; t += 256) {
            int q = t / npad, oo = Co + t % npad;
            int mat = q / C, c = q % C;
            wts[mat * CP + c * CoP + oo] = 0.f;
        }
    }
    // stage raw weights (coalesced global reads, LDS transpose writes)
    int twoCC = 2 * C * Co;
    for (int t = tid; t < twoCC; t += 256) {
        int o = t / (2 * C), c = t % (2 * C);
        float w = W[t], dw = Dw[t];
        if (c < C) {
            wts[c * CoP + o] = w;
            wts[2 * CP + c * CoP + o] = dw;
        } else {
            wts[CP + (c - C) * CoP + o] = w;
            wts[3 * CP + (c - C) * CoP + o] = dw;
        }
    }
    // stage point rows (coalesced)
    for (int t = tid; t < TILE * C3; t += 256) {
        int p = t / C3, cc = t % C3;
        xs[t] = X[(size_t)(bn0 + p) * rowStride + colOff + cc];
    }
    __syncthreads();
    // WB -= WA, DB -= DA in place
    for (int t = tid; t < CP; t += 256) {
        wts[CP + t] -= wts[t];
        wts[3 * CP + t] -= wts[2 * CP + t];
    }
    __syncthreads();

    int GPP = CoP >> 2;
    int items = TILE * GPP;
    for (int e = tid; e < items; e += 256) {
        int p = e / GPP, og = e - p * GPP;
        int o0 = og * 4;
        const float* xr = xs + p * C3;

        float aU[4][3], aV[4][3], aDu[4][3], aDv[4][3];
#pragma unroll
        for (int i = 0; i < 4; ++i)
#pragma unroll
            for (int j = 0; j < 3; ++j) {
                aU[i][j] = 0.f; aV[i][j] = 0.f; aDu[i][j] = 0.f; aDv[i][j] = 0.f;
            }

        for (int c = 0; c < C; ++c) {
            float x0 = xr[c * 3], x1 = xr[c * 3 + 1], x2 = xr[c * 3 + 2];
            const float* wp = wts + c * CoP + o0;
            float4 wa4 = *(const float4*)(wp);
            float4 wb4 = *(const float4*)(wp + CP);
            float4 da4 = *(const float4*)(wp + 2 * CP);
            float4 db4 = *(const float4*)(wp + 3 * CP);
            float wav[4] = {wa4.x, wa4.y, wa4.z, wa4.w};
            float wbv[4] = {wb4.x, wb4.y, wb4.z, wb4.w};
            float dav[4] = {da4.x, da4.y, da4.z, da4.w};
            float dbv[4] = {db4.x, db4.y, db4.z, db4.w};
#pragma unroll
            for (int i = 0; i < 4; ++i) {
                aU[i][0] += wav[i] * x0; aU[i][1] += wav[i] * x1; aU[i][2] += wav[i] * x2;
                aV[i][0] += wbv[i] * x0; aV[i][1] += wbv[i] * x1; aV[i][2] += wbv[i] * x2;
                aDu[i][0] += dav[i] * x0; aDu[i][1] += dav[i] * x1; aDu[i][2] += dav[i] * x2;
                aDv[i][0] += dbv[i] * x0; aDv[i][1] += dbv[i] * x1; aDv[i][2] += dbv[i] * x2;
            }
        }

        size_t base = ((size_t)(bn0 + p) * Co + o0) * 3;
#pragma unroll
        for (int i = 0; i < 4; ++i) {
            int o = o0 + i;
            if (o < Co) {
                size_t off = base + (size_t)i * 3;
                U[off] = aU[i][0]; U[off + 1] = aU[i][1]; U[off + 2] = aU[i][2];
                V[off] = aV[i][0]; V[off + 1] = aV[i][1]; V[off + 2] = aV[i][2];
                UD[off] = aDu[i][0]; UD[off + 1] = aDu[i][1]; UD[off + 2] = aDu[i][2];
                VD[off] = aDv[i][0]; VD[off + 1] = aDv[i][1]; VD[off + 2] = aDv[i][2];
            }
        }
    }
}

// ---------------- BN stats stage A (deterministic, R5 order + LDS staging) ----------------
__global__ void k_stats_edge_det(const float* __restrict__ U, const float* __restrict__ V,
                                 const int* __restrict__ idx, float* __restrict__ partials,
                                 int N, int Co, int BN) {
    int o = blockIdx.x;
    int s = blockIdx.y;
    int tid = threadIdx.x;
    int P = BN / SSPLIT;      // == N == 1024
    int g0 = s * P;

    __shared__ float Ush[3072];   // N * 3 (channel-o vectors for batch s)
    __shared__ float r1[256], r2[256];

    for (int t = tid; t < P; t += 256) {
        F3 u3 = *(const F3*)(U + ((size_t)(g0 + t) * Co + o) * 3);
        Ush[t * 3 + 0] = u3.x;
        Ush[t * 3 + 1] = u3.y;
        Ush[t * 3 + 2] = u3.z;
    }
    __syncthreads();

    float s1 = 0.f, s2 = 0.f;
    for (int pl = tid; pl < P; pl += 256) {
        int g = g0 + pl;                       // flattened b*N+n
        F3 v3 = *(const F3*)(V + ((size_t)g * Co + o) * 3);
        float v0 = v3.x, v1 = v3.y, v2 = v3.z;
        const int* ip = idx + (size_t)g * KNN;
        for (int kk = 0; kk < KNN; ++kk) {
            const float* Ur = Ush + ip[kk] * 3;   // idx is batch-local
            float p0 = Ur[0] + v0;
            float p1 = Ur[1] + v1;
            float p2 = Ur[2] + v2;
            float nm = sqrtf(p0 * p0 + p1 * p1 + p2 * p2) + EPSV;
            s1 += nm;
            s2 += nm * nm;
        }
    }
    r1[tid] = s1; r2[tid] = s2;
    __syncthreads();
    for (int st = 128; st > 0; st >>= 1) {
        if (tid < st) { r1[tid] += r1[tid + st]; r2[tid] += r2[tid + st]; }
        __syncthreads();
    }
    if (tid == 0) {
        partials[(o * SSPLIT + s) * 2] = r1[0];
        partials[(o * SSPLIT + s) * 2 + 1] = r2[0];
    }
}

// ---------------- fused stage-B: BN + dir leaky + mean-pool + cat transpose + sqnorm ----
// Block = (b, TN-point n-tile); computes all TN x Co outputs (per-output math
// verbatim from k_final_edge_p -> bit-identical values), stages into an LDS
// tile, then writes catp (coalesced rows), catn (transposed, TN-wide n
// segments == old k_transpose_cat writes), and xx for the next layer
// (ascending-c square-sum over the tile row == old fused-sqnorm chain).
__global__ void k_final_fused(const float* __restrict__ U, const float* __restrict__ V,
                              const float* __restrict__ UD, const float* __restrict__ VD,
                              const int* __restrict__ idx, const float* __restrict__ partials,
                              const float* __restrict__ gamma, const float* __restrict__ beta,
                              float* __restrict__ catp, float* __restrict__ catn,
                              float* __restrict__ xx,
                              int N, int Co, int colOff, float cnt, int doSq) {
    int b = blockIdx.y;
    int n0 = blockIdx.x * TN;
    int tid = threadIdx.x;
    int CC = Co * 3;

    __shared__ float tile[TN * 255];    // TN x CC, CC <= 255
    __shared__ float muS[85], invS[85];

    // per-channel mu/inv: identical fixed-order SSPLIT sum as before
    for (int o = tid; o < Co; o += 256) {
        float s1 = 0.f, s2 = 0.f;
        for (int s = 0; s < SSPLIT; ++s) {
            s1 += partials[(o * SSPLIT + s) * 2];
            s2 += partials[(o * SSPLIT + s) * 2 + 1];
        }
        float mu = s1 / cnt;
        float var = s2 / cnt - mu * mu;
        muS[o] = mu;
        invS[o] = rsqrtf(var + 1e-5f);
    }
    __syncthreads();

    const float invk = 1.f / (float)KNN;
    int items = TN * Co;
    for (int e = tid; e < items; e += 256) {
        int nl = e / Co, o = e - nl * Co;
        int n = n0 + nl;
        float mu = muS[o], inv = invS[o];
        float gmm = gamma[o], bt = beta[o];

        size_t ctr = ((size_t)(b * N + n) * Co + o) * 3;
        F3 vc = *(const F3*)(V + ctr);
        F3 wc = *(const F3*)(VD + ctr);
        float v0 = vc.x, v1 = vc.y, v2 = vc.z;
        float w0 = wc.x, w1 = wc.y, w2 = wc.z;
        const int* ip = idx + ((size_t)b * N + n) * KNN;

        float a0 = 0.f, a1 = 0.f, a2 = 0.f;
        for (int kk = 0; kk < KNN; ++kk) {
            int m = ip[kk];
            size_t nb = ((size_t)(b * N + m) * Co + o) * 3;
            F3 un = *(const F3*)(U + nb);
            F3 dn = *(const F3*)(UD + nb);
            float p0 = un.x + v0;
            float p1 = un.y + v1;
            float p2 = un.z + v2;
            float nm = sqrtf(p0 * p0 + p1 * p1 + p2 * p2) + EPSV;
            float nbn = (nm - mu) * inv * gmm + bt;
            float sc = nbn / nm;
            p0 *= sc; p1 *= sc; p2 *= sc;
            float d0 = dn.x + w0;
            float d1 = dn.y + w1;
            float d2 = dn.z + w2;
            float dot = p0 * d0 + p1 * d1 + p2 * d2;
            if (dot >= 0.f) {
                a0 += p0; a1 += p1; a2 += p2;
            } else {
                float f = dot / (d0 * d0 + d1 * d1 + d2 * d2 + EPSV);
                a0 += NS * p0 + (1.f - NS) * (p0 - f * d0);
                a1 += NS * p1 + (1.f - NS) * (p1 - f * d1);
                a2 += NS * p2 + (1.f - NS) * (p2 - f * d2);
            }
        }
        tile[nl * CC + o * 3 + 0] = a0 * invk;
        tile[nl * CC + o * 3 + 1] = a1 * invk;
        tile[nl * CC + o * 3 + 2] = a2 * invk;
    }
    __syncthreads();

    // catp: coalesced row writes
    for (int t = tid; t < TN * CC; t += 256) {
        int nl = t / CC, c = t - nl * CC;
        catp[(size_t)(b * N + n0 + nl) * CROW + colOff + c] = tile[nl * CC + c];
    }
    // catn: transposed writes, TN consecutive n per c
    for (int t = tid; t < TN * CC; t += 256) {
        int c = t >> 3, nl = t & (TN - 1);   // TN == 8
        catn[(size_t)b * CROW * N + (size_t)(colOff + c) * N + n0 + nl] = tile[nl * CC + c];
    }
    // next-layer sqnorm: ascending-c chain over the tile row (== old order)
    if (doSq && tid < TN) {
        const float* row = tile + tid * CC;
        float s = 0.f;
        for (int c = 0; c < CC; ++c) {
            float v = row[c];
            s += v * v;
        }
        xx[(size_t)b * N + n0 + tid] = s;
    }
}

// ---------------- plain matmul (layer 5, n-major): U = W*x, j-fused + 2-n tile ----------
// W and Dw launches merged: last blockIdx.y tile runs the Dw (Cout=1) path.
__global__ void k_matmul_plain(const float* __restrict__ X, const float* __restrict__ W,
                               const float* __restrict__ Dw,
                               float* __restrict__ U, float* __restrict__ Ud,
                               int N, int Cin, int Cout, long batchStride, long sliceOff) {
    int ot = blockIdx.y;
    int b = blockIdx.z;
    int tid = threadIdx.x;
    int n = blockIdx.x * 512 + 2 * tid;

    const float* Wp; float* Up; int CoutE; int o0;
    if (ot == (int)gridDim.y - 1) {   // Dw path
        Wp = Dw; Up = Ud; CoutE = 1; o0 = 0;
    } else {
        Wp = W; Up = U; CoutE = Cout; o0 = ot * OT;
    }

    __shared__ __align__(16) float wsm[OT][176];  // Cin <= 169; stride 176 keeps rows 16B-aligned
    for (int t = tid; t < OT * Cin; t += 256) {
        int oo = t / Cin, c = t % Cin;
        int o = o0 + oo;
        wsm[oo][c] = (o < CoutE) ? Wp[(size_t)o * Cin + c] : 0.f;
    }
    __syncthreads();

    const float* Xp = X + (size_t)b * batchStride + sliceOff + n;
    float au[OT][3][2];
#pragma unroll
    for (int oo = 0; oo < OT; ++oo)
#pragma unroll
        for (int j = 0; j < 3; ++j) {
            au[oo][j][0] = 0.f; au[oo][j][1] = 0.f;
        }

    int c = 0;
    for (; c + 4 <= Cin; c += 4) {
        float2 xv[4][3];
#pragma unroll
        for (int cc = 0; cc < 4; ++cc)
#pragma unroll
            for (int j = 0; j < 3; ++j)
                xv[cc][j] = *(const float2*)(Xp + ((size_t)(c + cc) * 3 + j) * N);
#pragma unroll
        for (int oo = 0; oo < OT; ++oo) {
            float4 w4 = *(const float4*)&wsm[oo][c];
            float wv[4] = {w4.x, w4.y, w4.z, w4.w};
#pragma unroll
            for (int j = 0; j < 3; ++j) {
#pragma unroll
                for (int cc = 0; cc < 4; ++cc) {
                    au[oo][j][0] += wv[cc] * xv[cc][j].x;
                    au[oo][j][1] += wv[cc] * xv[cc][j].y;
                }
            }
        }
    }
    for (; c < Cin; ++c) {
        float2 xv[3];
#pragma unroll
        for (int j = 0; j < 3; ++j)
            xv[j] = *(const float2*)(Xp + ((size_t)c * 3 + j) * N);
#pragma unroll
        for (int oo = 0; oo < OT; ++oo) {
            float wv = wsm[oo][c];
#pragma unroll
            for (int j = 0; j < 3; ++j) {
                au[oo][j][0] += wv * xv[j].x;
                au[oo][j][1] += wv * xv[j].y;
            }
        }
    }
#pragma unroll
    for (int oo = 0; oo < OT; ++oo) {
        int o = o0 + oo;
        if (o < CoutE) {
#pragma unroll
            for (int j = 0; j < 3; ++j) {
                float2 st; st.x = au[oo][j][0]; st.y = au[oo][j][1];
                *(float2*)&Up[(((size_t)b * CoutE + o) * 3 + j) * N + n] = st;
            }
        }
    }
}

// ---------------- layer-5 stats (deterministic): one block per channel ----------------
__global__ void k_stats_plain_det(const float* __restrict__ U, float* __restrict__ mv,
                                  int N, int Cout, int BN, float cnt) {
    int o = blockIdx.x;
    int tid = threadIdx.x;
    float s1 = 0.f, s2 = 0.f;
    for (int g = tid; g < BN; g += 256) {
        int b = g / N, n = g % N;
        const float* Ub = U + (((size_t)b * Cout + o) * 3) * N;
        float p0 = Ub[n], p1 = Ub[(size_t)N + n], p2 = Ub[(size_t)2 * N + n];
        float nm = sqrtf(p0 * p0 + p1 * p1 + p2 * p2) + EPSV;
        s1 += nm;
        s2 += nm * nm;
    }
    __shared__ float r1[256], r2[256];
    r1[tid] = s1; r2[tid] = s2;
    __syncthreads();
    for (int st = 128; st > 0; st >>= 1) {
        if (tid < st) { r1[tid] += r1[tid + st]; r2[tid] += r2[tid + st]; }
        __syncthreads();
    }
    if (tid == 0) {
        float mu = r1[0] / cnt;
        float var = r2[0] / cnt - mu * mu;
        mv[2 * o] = mu;
        mv[2 * o + 1] = rsqrtf(var + 1e-5f);
    }
}

// ---------------- layer-5 final: BN + dir leaky (1 dir channel) -> d_out ----------------
__global__ void k_final_plain(const float* __restrict__ U, const float* __restrict__ Dv,
                              const float* __restrict__ mv,
                              const float* __restrict__ gamma, const float* __restrict__ beta,
                              float* __restrict__ out, int N, int Cout) {
    int b = blockIdx.z, o = blockIdx.y, tid = threadIdx.x;
    int n = blockIdx.x * 256 + tid;
    float mu = mv[2 * o];
    float inv = mv[2 * o + 1];
    float g = gamma[o], bt = beta[o];

    const float* Ub = U + (((size_t)b * Cout + o) * 3) * N;
    float p0 = Ub[n], p1 = Ub[(size_t)N + n], p2 = Ub[(size_t)2 * N + n];
    float nm = sqrtf(p0 * p0 + p1 * p1 + p2 * p2) + EPSV;
    float nbn = (nm - mu) * inv * g + bt;
    float sc = nbn / nm;
    p0 *= sc; p1 *= sc; p2 *= sc;

    float d0 = Dv[((size_t)b * 3 + 0) * N + n];
    float d1 = Dv[((size_t)b * 3 + 1) * N + n];
    float d2 = Dv[((size_t)b * 3 + 2) * N + n];
    float dot = p0 * d0 + p1 * d1 + p2 * d2;
    float o0, o1, o2;
    if (dot >= 0.f) {
        o0 = p0; o1 = p1; o2 = p2;
    } else {
        float f = dot / (d0 * d0 + d1 * d1 + d2 * d2 + EPSV);
        o0 = NS * p0 + (1.f - NS) * (p0 - f * d0);
        o1 = NS * p1 + (1.f - NS) * (p1 - f * d1);
        o2 = NS * p2 + (1.f - NS) * (p2 - f * d2);
    }
    size_t ob = (((size_t)b * Cout + o) * 3) * N + n;
    out[ob] = o0;
    out[ob + (size_t)N] = o1;
    out[ob + (size_t)2 * N] = o2;
}

extern "C" void kernel_launch(void* const* d_in, const int* in_sizes, int n_in,
                              void* d_out, int out_size, void* d_ws, size_t ws_size,
                              hipStream_t stream) {
    (void)in_sizes; (void)n_in; (void)out_size; (void)ws_size;
    const int B = 8, N = 1024;

    const float* x = (const float*)d_in[0];
    const float* W[5]; const float* Dw[5]; const float* G[5]; const float* Bt[5];
    for (int l = 0; l < 5; ++l) {
        W[l]  = (const float*)d_in[1 + 4 * l];
        Dw[l] = (const float*)d_in[2 + 4 * l];
        G[l]  = (const float*)d_in[3 + 4 * l];
        Bt[l] = (const float*)d_in[4 + 4 * l];
    }

    float* ws = (float*)d_ws;
    size_t off = 0;
    float* xt = ws + off;     off += (size_t)B * 3 * N;
    int* idx = (int*)(ws + off); off += (size_t)B * N * KNN;
    float* catp = ws + off;   off += (size_t)B * N * CROW;
    float* catn = ws + off;   off += (size_t)B * N * CROW;
    float* Up = ws + off;     off += (size_t)B * N * 85 * 3;
    float* Vp = ws + off;     off += (size_t)B * N * 85 * 3;
    float* UDp = ws + off;    off += (size_t)B * N * 85 * 3;
    float* VDp = ws + off;    off += (size_t)B * N * 85 * 3;
    float* U5 = ws + off;     off += (size_t)B * 341 * 3 * N;
    float* d5buf = ws + off;  off += (size_t)B * 3 * N;
    float* xx = ws + off;     off += (size_t)B * N;           // 16B-aligned (all prior multiples of 4)
    float* partials = ws + off; off += (size_t)341 * SSPLIT * 2;
    float* mv = ws + off;     off += 2 * 341;

    k_transpose<<<(B * N + 255) / 256, 256, 0, stream>>>(x, xt, xx, B, N);

    const int Cin_[4]  = {1, 21, 21, 42};
    const int Cout_[4] = {21, 21, 42, 85};
    const int inOff_[4] = {-1, 0, 21, 42};
    const int outOff_[4] = {0, 21, 42, 84};
    const int Tile_[4] = {32, 32, 32, 8};   // LDS budget: L4 needs small x-tile

    const int BN = B * N;

    for (int l = 0; l < 4; ++l) {
        int C = Cin_[l], Co = Cout_[l];
        int D = C * 3;
        int CoP = (Co + 3) & ~3;
        int TILE = Tile_[l];

        // n-major source for knn
        const float* Xn; long bs, so;
        if (inOff_[l] < 0) { Xn = xt; bs = (long)3 * N; so = 0; }
        else { Xn = catn; bs = (long)CROW * N; so = (long)inOff_[l] * 3 * N; }

        // point-major source for matmul
        const float* Xp; int rs, co;
        if (inOff_[l] < 0) { Xp = x; rs = 3; co = 0; }
        else { Xp = catp; rs = CROW; co = inOff_[l] * 3; }

        // xx for this layer was produced by k_transpose (l=0) or the previous
        // layer's k_final_fused (l>=1)
        dim3 gk(N / QT, B);
        k_knn<<<gk, 256, 0, stream>>>(Xn, xx, idx, N, D, bs, so);

        size_t smemB = (size_t)(4 * C * CoP + TILE * C * 3) * sizeof(float);
        k_matmul_pair_lds<<<(B * N) / TILE, 256, smemB, stream>>>(
            Xp, W[l], Dw[l], Up, Vp, UDp, VDp, C, Co, CoP, TILE, rs, co);

        dim3 gst(Co, SSPLIT);
        k_stats_edge_det<<<gst, 256, 0, stream>>>(Up, Vp, idx, partials, N, Co, BN);

        int doSq = (l < 3) ? 1 : 0;   // layers 0-2 produce xx for the next layer
        dim3 gf(N / TN, B);
        k_final_fused<<<gf, 256, 0, stream>>>(
            Up, Vp, UDp, VDp, idx, partials, G[l], Bt[l],
            catp, catn, xx, N, Co, outOff_[l] * 3,
            (float)((size_t)BN * KNN), doSq);
    }

    // layer 5 (reads catn n-major); W and Dw matmuls merged into one launch
    {
        long bs = (long)CROW * N, so = 0;
        dim3 gm5(N / 512, (341 + OT - 1) / OT + 1, B);   // +1: Dw tile
        k_matmul_plain<<<gm5, 256, 0, stream>>>(catn, W[4], Dw[4], U5, d5buf,
                                                N, 169, 341, bs, so);
        k_stats_plain_det<<<341, 256, 0, stream>>>(U5, mv, N, 341, BN, (float)BN);
        dim3 gs5(N / 256, 341, B);
        k_final_plain<<<gs5, 256, 0, stream>>>(U5, d5buf, mv, G[4], Bt[4],
                                               (float*)d_out, N, 341);
    }
}

// Round 10
// 664.537 us; speedup vs baseline: 1.1615x; 1.0183x over previous
//
#include <hip/hip_runtime.h>
#include <math.h>

#define KNN 20
#define NS 0.2f
#define EPSV 1e-6f
#define QT 4
#define OT 8
#define TN 8       // n-tile of k_final_fused
#define CROW 507   // 169*3, cat row stride (floats)
#define SSPLIT 8   // stats splits (== B; split s covers batch s exactly)

struct F3 { float x, y, z; };   // 12-byte vector load (global_load_dwordx3)

extern __shared__ __align__(16) float smem[];

// ---------------- transpose (B,N,3) -> (B,3,N) + fused sqnorm (layer-1) ----------------
__global__ void k_transpose(const float* __restrict__ x, float* __restrict__ xt,
                            float* __restrict__ xx, int B, int N) {
    int i = blockIdx.x * blockDim.x + threadIdx.x;
    if (i >= B * N) return;
    int b = i / N, n = i % N;
    const float* src = x + (size_t)(b * N + n) * 3;
    float* dst = xt + (size_t)b * 3 * N + n;
    float s0 = src[0], s1 = src[1], s2 = src[2];
    dst[0] = s0;
    dst[(size_t)N] = s1;
    dst[(size_t)2 * N] = s2;
    float s = 0.f;
    s += s0 * s0;
    s += s1 * s1;
    s += s2 * s2;
    xx[i] = s;
}

// ---------------- knn: 4 waves/block, wave-local top-k ----------------
// pd compute unchanged (bit-identical). Selection: per-lane sorted u64 keys,
// Batcher-sorted once; keys 8-15 spill to pd[wave]'s dead LDS row. Extraction:
// butterfly max on the 32-bit HI word only (6 bpermutes, was 12 for u64),
// then ballot index-resolve: single-match (common) -> uniform-lane shfl
// (v_readlane, no LDS op); tie -> rare wave-uniform lo-butterfly fallback.
// Winner == max u64 key in all cases -> bit-identical indices.
__global__ void k_knn(const float* __restrict__ X, const float* __restrict__ xx,
                      int* __restrict__ idx,
                      int N, int D, long batchStride, long sliceOff) {
    int b = blockIdx.y;
    int q0 = blockIdx.x * QT;
    int tid = threadIdx.x;
    int lane = tid & 63;
    int wave = tid >> 6;

    __shared__ __align__(16) float qf[128 * QT];   // [d][q], D <= 126
    __shared__ __align__(16) float pd[QT][1024];   // N == 1024

    const float* Xb = X + (size_t)b * batchStride + sliceOff;
    const float* xxb = xx + (size_t)b * N;

    for (int t = tid; t < QT * D; t += 256) {
        int d = t >> 2, q = t & 3;
        qf[d * QT + q] = Xb[(size_t)d * N + (q0 + q)];
    }
    __syncthreads();

    float a0x = 0.f, a0y = 0.f, a0z = 0.f, a0w = 0.f;
    float a1x = 0.f, a1y = 0.f, a1z = 0.f, a1w = 0.f;
    float a2x = 0.f, a2y = 0.f, a2z = 0.f, a2w = 0.f;
    float a3x = 0.f, a3y = 0.f, a3z = 0.f, a3w = 0.f;

    const float* mbase = Xb + 4 * tid;
#pragma unroll 3
    for (int d = 0; d < D; ++d) {
        float4 xm = *(const float4*)(mbase + (size_t)d * N);
        float4 qv = *(const float4*)(qf + d * QT);
        a0x += qv.x * xm.x; a0y += qv.x * xm.y; a0z += qv.x * xm.z; a0w += qv.x * xm.w;
        a1x += qv.y * xm.x; a1y += qv.y * xm.y; a1z += qv.y * xm.z; a1w += qv.y * xm.w;
        a2x += qv.z * xm.x; a2y += qv.z * xm.y; a2z += qv.z * xm.z; a2w += qv.z * xm.w;
        a3x += qv.w * xm.x; a3y += qv.w * xm.y; a3z += qv.w * xm.z; a3w += qv.w * xm.w;
    }

    {
        float4 m2 = *(const float4*)(xxb + 4 * tid);   // ||x_m||^2, 4 m's
        float4 qn = *(const float4*)(xxb + q0);        // ||x_q||^2, 4 q's
        float4 v;
        v.x = 2.f * a0x - qn.x - m2.x; v.y = 2.f * a0y - qn.x - m2.y;
        v.z = 2.f * a0z - qn.x - m2.z; v.w = 2.f * a0w - qn.x - m2.w;
        *(float4*)&pd[0][4 * tid] = v;
        v.x = 2.f * a1x - qn.y - m2.x; v.y = 2.f * a1y - qn.y - m2.y;
        v.z = 2.f * a1z - qn.y - m2.z; v.w = 2.f * a1w - qn.y - m2.w;
        *(float4*)&pd[1][4 * tid] = v;
        v.x = 2.f * a2x - qn.z - m2.x; v.y = 2.f * a2y - qn.z - m2.y;
        v.z = 2.f * a2z - qn.z - m2.z; v.w = 2.f * a2w - qn.z - m2.w;
        *(float4*)&pd[2][4 * tid] = v;
        v.x = 2.f * a3x - qn.w - m2.x; v.y = 2.f * a3y - qn.w - m2.y;
        v.z = 2.f * a3z - qn.w - m2.z; v.w = 2.f * a3w - qn.w - m2.w;
        *(float4*)&pd[3][4 * tid] = v;
    }
    __syncthreads();

    // ---- build sortable keys: hi = orderable(float bits), lo = 1023 - idx ----
    unsigned long long key[16];
#pragma unroll
    for (int t = 0; t < 16; ++t) {
        unsigned u = __float_as_uint(pd[wave][t * 64 + lane]);
        u ^= (unsigned)((int)u >> 31) | 0x80000000u;
        unsigned lo = (unsigned)(1023 - t * 64) - (unsigned)lane;
        key[t] = ((unsigned long long)u << 32) | (unsigned long long)lo;
    }

    // ---- per-lane descending sort: explicit Batcher odd-even mergesort n=16 ----
#define CE(a, b)                                        \
    {                                                   \
        unsigned long long ka = key[a], kb = key[b];    \
        bool sw = ka < kb;                              \
        key[a] = sw ? kb : ka;                          \
        key[b] = sw ? ka : kb;                          \
    }
    CE(0,1) CE(2,3) CE(4,5) CE(6,7) CE(8,9) CE(10,11) CE(12,13) CE(14,15)
    CE(0,2) CE(1,3) CE(4,6) CE(5,7) CE(8,10) CE(9,11) CE(12,14) CE(13,15)
    CE(1,2) CE(5,6) CE(9,10) CE(13,14)
    CE(0,4) CE(1,5) CE(2,6) CE(3,7) CE(8,12) CE(9,13) CE(10,14) CE(11,15)
    CE(2,4) CE(3,5) CE(10,12) CE(11,13)
    CE(1,2) CE(3,4) CE(5,6) CE(9,10) CE(11,12) CE(13,14)
    CE(0,8) CE(1,9) CE(2,10) CE(3,11) CE(4,12) CE(5,13) CE(6,14) CE(7,15)
    CE(4,8) CE(5,9) CE(6,10) CE(7,11)
    CE(2,4) CE(3,5) CE(6,8) CE(7,9) CE(10,12) CE(11,13)
    CE(1,2) CE(3,4) CE(5,6) CE(7,8) CE(9,10) CE(11,12) CE(13,14)
#undef CE

    // ---- spill keys 8..15 to pd[wave]'s row (dead after key build) ----
    __syncthreads();
    unsigned long long* kl = (unsigned long long*)&pd[wave][0];  // 512 u64, wave-private
#pragma unroll
    for (int t = 8; t < 16; ++t) kl[(t - 8) * 64 + lane] = key[t];
    int nspill = 0;

    // ---- 20 extractions: hi-word butterfly + ballot resolve + owner pop ----
    long outBase = ((long)b * N + q0 + wave) * KNN;
    for (int it = 0; it < KNN; ++it) {
        unsigned myh = (unsigned)(key[0] >> 32);
        unsigned mylo = (unsigned)(key[0] & 0xFFFFFFFFull);
        unsigned bh = myh;
#pragma unroll
        for (int off = 32; off >= 1; off >>= 1) {
            unsigned oh = __shfl_xor(bh, off, 64);
            if (oh > bh) bh = oh;
        }
        // bh = max hi across wave (uniform)
        unsigned long long mask = __ballot(myh == bh);
        unsigned ml;
        if (__popcll(mask) == 1) {
            int src = (int)(__ffsll((long long)mask) - 1);   // uniform -> readlane
            ml = __shfl(mylo, src, 64);
        } else {
            // rare tie: masked lo-butterfly (lo distinct; max lo = winner)
            unsigned cand = (myh == bh) ? mylo : 0u;
#pragma unroll
            for (int off = 32; off >= 1; off >>= 1) {
                unsigned oc = __shfl_xor(cand, off, 64);
                if (oc > cand) cand = oc;
            }
            ml = cand;
        }
        int bi = 1023 - (int)(ml & 1023u);
        if (lane == 0) idx[outBase + it] = bi;
        if ((bi & 63) == lane) {
            key[0] = key[1]; key[1] = key[2]; key[2] = key[3]; key[3] = key[4];
            key[4] = key[5]; key[5] = key[6]; key[6] = key[7];
            int sidx = nspill < 8 ? nspill : 7;            // clamp: stay in wave's 4KB row
            unsigned long long nv = kl[sidx * 64 + lane];
            key[7] = (nspill < 8) ? nv : 0ull;             // sentinel below all real keys
            nspill++;
        }
    }
}

// ---------------- LDS-staged point-major pair matmul ----------------
__global__ void k_matmul_pair_lds(const float* __restrict__ X, const float* __restrict__ W,
                                  const float* __restrict__ Dw,
                                  float* __restrict__ U, float* __restrict__ V,
                                  float* __restrict__ UD, float* __restrict__ VD,
                                  int C, int Co, int CoP, int TILE,
                                  int rowStride, int colOff) {
    const int CP = C * CoP;
    float* wts = smem;            // 4*CP: [WA | WB-WA | DA | DB-DA], each [c][o]
    float* xs = smem + 4 * CP;    // TILE * C * 3

    int tid = threadIdx.x;
    int bn0 = blockIdx.x * TILE;  // flattened b*N+n base
    int C3 = C * 3;

    // zero padded o-lanes
    int npad = CoP - Co;
    if (npad) {
        for (int t = tid; t < 4 * C * npad; t += 256) {
            int q = t / npad, oo = Co + t % npad;
            int mat = q / C, c = q % C;
            wts[mat * CP + c * CoP + oo] = 0.f;
        }
    }
    // stage raw weights (coalesced global reads, LDS transpose writes)
    int twoCC = 2 * C * Co;
    for (int t = tid; t < twoCC; t += 256) {
        int o = t / (2 * C), c = t % (2 * C);
        float w = W[t], dw = Dw[t];
        if (c < C) {
            wts[c * CoP + o] = w;
            wts[2 * CP + c * CoP + o] = dw;
        } else {
            wts[CP + (c - C) * CoP + o] = w;
            wts[3 * CP + (c - C) * CoP + o] = dw;
        }
    }
    // stage point rows (coalesced)
    for (int t = tid; t < TILE * C3; t += 256) {
        int p = t / C3, cc = t % C3;
        xs[t] = X[(size_t)(bn0 + p) * rowStride + colOff + cc];
    }
    __syncthreads();
    // WB -= WA, DB -= DA in place
    for (int t = tid; t < CP; t += 256) {
        wts[CP + t] -= wts[t];
        wts[3 * CP + t] -= wts[2 * CP + t];
    }
    __syncthreads();

    int GPP = CoP >> 2;
    int items = TILE * GPP;
    for (int e = tid; e < items; e += 256) {
        int p = e / GPP, og = e - p * GPP;
        int o0 = og * 4;
        const float* xr = xs + p * C3;

        float aU[4][3], aV[4][3], aDu[4][3], aDv[4][3];
#pragma unroll
        for (int i = 0; i < 4; ++i)
#pragma unroll
            for (int j = 0; j < 3; ++j) {
                aU[i][j] = 0.f; aV[i][j] = 0.f; aDu[i][j] = 0.f; aDv[i][j] = 0.f;
            }

        for (int c = 0; c < C; ++c) {
            float x0 = xr[c * 3], x1 = xr[c * 3 + 1], x2 = xr[c * 3 + 2];
            const float* wp = wts + c * CoP + o0;
            float4 wa4 = *(const float4*)(wp);
            float4 wb4 = *(const float4*)(wp + CP);
            float4 da4 = *(const float4*)(wp + 2 * CP);
            float4 db4 = *(const float4*)(wp + 3 * CP);
            float wav[4] = {wa4.x, wa4.y, wa4.z, wa4.w};
            float wbv[4] = {wb4.x, wb4.y, wb4.z, wb4.w};
            float dav[4] = {da4.x, da4.y, da4.z, da4.w};
            float dbv[4] = {db4.x, db4.y, db4.z, db4.w};
#pragma unroll
            for (int i = 0; i < 4; ++i) {
                aU[i][0] += wav[i] * x0; aU[i][1] += wav[i] * x1; aU[i][2] += wav[i] * x2;
                aV[i][0] += wbv[i] * x0; aV[i][1] += wbv[i] * x1; aV[i][2] += wbv[i] * x2;
                aDu[i][0] += dav[i] * x0; aDu[i][1] += dav[i] * x1; aDu[i][2] += dav[i] * x2;
                aDv[i][0] += dbv[i] * x0; aDv[i][1] += dbv[i] * x1; aDv[i][2] += dbv[i] * x2;
            }
        }

        size_t base = ((size_t)(bn0 + p) * Co + o0) * 3;
#pragma unroll
        for (int i = 0; i < 4; ++i) {
            int o = o0 + i;
            if (o < Co) {
                size_t off = base + (size_t)i * 3;
                U[off] = aU[i][0]; U[off + 1] = aU[i][1]; U[off + 2] = aU[i][2];
                V[off] = aV[i][0]; V[off + 1] = aV[i][1]; V[off + 2] = aV[i][2];
                UD[off] = aDu[i][0]; UD[off + 1] = aDu[i][1]; UD[off + 2] = aDu[i][2];
                VD[off] = aDv[i][0]; VD[off + 1] = aDv[i][1]; VD[off + 2] = aDv[i][2];
            }
        }
    }
}

// ---------------- BN stats stage A (deterministic, R5 order + LDS staging) ----------------
__global__ void k_stats_edge_det(const float* __restrict__ U, const float* __restrict__ V,
                                 const int* __restrict__ idx, float* __restrict__ partials,
                                 int N, int Co, int BN) {
    int o = blockIdx.x;
    int s = blockIdx.y;
    int tid = threadIdx.x;
    int P = BN / SSPLIT;      // == N == 1024
    int g0 = s * P;

    __shared__ float Ush[3072];   // N * 3 (channel-o vectors for batch s)
    __shared__ float r1[256], r2[256];

    for (int t = tid; t < P; t += 256) {
        F3 u3 = *(const F3*)(U + ((size_t)(g0 + t) * Co + o) * 3);
        Ush[t * 3 + 0] = u3.x;
        Ush[t * 3 + 1] = u3.y;
        Ush[t * 3 + 2] = u3.z;
    }
    __syncthreads();

    float s1 = 0.f, s2 = 0.f;
    for (int pl = tid; pl < P; pl += 256) {
        int g = g0 + pl;                       // flattened b*N+n
        F3 v3 = *(const F3*)(V + ((size_t)g * Co + o) * 3);
        float v0 = v3.x, v1 = v3.y, v2 = v3.z;
        const int* ip = idx + (size_t)g * KNN;
        for (int kk = 0; kk < KNN; ++kk) {
            const float* Ur = Ush + ip[kk] * 3;   // idx is batch-local
            float p0 = Ur[0] + v0;
            float p1 = Ur[1] + v1;
            float p2 = Ur[2] + v2;
            float nm = sqrtf(p0 * p0 + p1 * p1 + p2 * p2) + EPSV;
            s1 += nm;
            s2 += nm * nm;
        }
    }
    r1[tid] = s1; r2[tid] = s2;
    __syncthreads();
    for (int st = 128; st > 0; st >>= 1) {
        if (tid < st) { r1[tid] += r1[tid + st]; r2[tid] += r2[tid + st]; }
        __syncthreads();
    }
    if (tid == 0) {
        partials[(o * SSPLIT + s) * 2] = r1[0];
        partials[(o * SSPLIT + s) * 2 + 1] = r2[0];
    }
}

// ---------------- fused stage-B: BN + dir leaky + mean-pool + cat transpose + sqnorm ----
__global__ void k_final_fused(const float* __restrict__ U, const float* __restrict__ V,
                              const float* __restrict__ UD, const float* __restrict__ VD,
                              const int* __restrict__ idx, const float* __restrict__ partials,
                              const float* __restrict__ gamma, const float* __restrict__ beta,
                              float* __restrict__ catp, float* __restrict__ catn,
                              float* __restrict__ xx,
                              int N, int Co, int colOff, float cnt, int doSq) {
    int b = blockIdx.y;
    int n0 = blockIdx.x * TN;
    int tid = threadIdx.x;
    int CC = Co * 3;

    __shared__ float tile[TN * 255];    // TN x CC, CC <= 255
    __shared__ float muS[85], invS[85];

    // per-channel mu/inv: identical fixed-order SSPLIT sum as before
    for (int o = tid; o < Co; o += 256) {
        float s1 = 0.f, s2 = 0.f;
        for (int s = 0; s < SSPLIT; ++s) {
            s1 += partials[(o * SSPLIT + s) * 2];
            s2 += partials[(o * SSPLIT + s) * 2 + 1];
        }
        float mu = s1 / cnt;
        float var = s2 / cnt - mu * mu;
        muS[o] = mu;
        invS[o] = rsqrtf(var + 1e-5f);
    }
    __syncthreads();

    const float invk = 1.f / (float)KNN;
    int items = TN * Co;
    for (int e = tid; e < items; e += 256) {
        int nl = e / Co, o = e - nl * Co;
        int n = n0 + nl;
        float mu = muS[o], inv = invS[o];
        float gmm = gamma[o], bt = beta[o];

        size_t ctr = ((size_t)(b * N + n) * Co + o) * 3;
        F3 vc = *(const F3*)(V + ctr);
        F3 wc = *(const F3*)(VD + ctr);
        float v0 = vc.x, v1 = vc.y, v2 = vc.z;
        float w0 = wc.x, w1 = wc.y, w2 = wc.z;
        const int* ip = idx + ((size_t)b * N + n) * KNN;

        float a0 = 0.f, a1 = 0.f, a2 = 0.f;
        for (int kk = 0; kk < KNN; ++kk) {
            int m = ip[kk];
            size_t nb = ((size_t)(b * N + m) * Co + o) * 3;
            F3 un = *(const F3*)(U + nb);
            F3 dn = *(const F3*)(UD + nb);
            float p0 = un.x + v0;
            float p1 = un.y + v1;
            float p2 = un.z + v2;
            float nm = sqrtf(p0 * p0 + p1 * p1 + p2 * p2) + EPSV;
            float nbn = (nm - mu) * inv * gmm + bt;
            float sc = nbn / nm;
            p0 *= sc; p1 *= sc; p2 *= sc;
            float d0 = dn.x + w0;
            float d1 = dn.y + w1;
            float d2 = dn.z + w2;
            float dot = p0 * d0 + p1 * d1 + p2 * d2;
            if (dot >= 0.f) {
                a0 += p0; a1 += p1; a2 += p2;
            } else {
                float f = dot / (d0 * d0 + d1 * d1 + d2 * d2 + EPSV);
                a0 += NS * p0 + (1.f - NS) * (p0 - f * d0);
                a1 += NS * p1 + (1.f - NS) * (p1 - f * d1);
                a2 += NS * p2 + (1.f - NS) * (p2 - f * d2);
            }
        }
        tile[nl * CC + o * 3 + 0] = a0 * invk;
        tile[nl * CC + o * 3 + 1] = a1 * invk;
        tile[nl * CC + o * 3 + 2] = a2 * invk;
    }
    __syncthreads();

    // catp: coalesced row writes
    for (int t = tid; t < TN * CC; t += 256) {
        int nl = t / CC, c = t - nl * CC;
        catp[(size_t)(b * N + n0 + nl) * CROW + colOff + c] = tile[nl * CC + c];
    }
    // catn: transposed writes, TN consecutive n per c
    for (int t = tid; t < TN * CC; t += 256) {
        int c = t >> 3, nl = t & (TN - 1);   // TN == 8
        catn[(size_t)b * CROW * N + (size_t)(colOff + c) * N + n0 + nl] = tile[nl * CC + c];
    }
    // next-layer sqnorm: ascending-c chain over the tile row (== old order)
    if (doSq && tid < TN) {
        const float* row = tile + tid * CC;
        float s = 0.f;
        for (int c = 0; c < CC; ++c) {
            float v = row[c];
            s += v * v;
        }
        xx[(size_t)b * N + n0 + tid] = s;
    }
}

// ---------------- plain matmul (layer 5, n-major): U = W*x, j-fused + 2-n tile ----------
__global__ void k_matmul_plain(const float* __restrict__ X, const float* __restrict__ W,
                               const float* __restrict__ Dw,
                               float* __restrict__ U, float* __restrict__ Ud,
                               int N, int Cin, int Cout, long batchStride, long sliceOff) {
    int ot = blockIdx.y;
    int b = blockIdx.z;
    int tid = threadIdx.x;
    int n = blockIdx.x * 512 + 2 * tid;

    const float* Wp; float* Up; int CoutE; int o0;
    if (ot == (int)gridDim.y - 1) {   // Dw path
        Wp = Dw; Up = Ud; CoutE = 1; o0 = 0;
    } else {
        Wp = W; Up = U; CoutE = Cout; o0 = ot * OT;
    }

    __shared__ __align__(16) float wsm[OT][176];  // Cin <= 169; stride 176 keeps rows 16B-aligned
    for (int t = tid; t < OT * Cin; t += 256) {
        int oo = t / Cin, c = t % Cin;
        int o = o0 + oo;
        wsm[oo][c] = (o < CoutE) ? Wp[(size_t)o * Cin + c] : 0.f;
    }
    __syncthreads();

    const float* Xp = X + (size_t)b * batchStride + sliceOff + n;
    float au[OT][3][2];
#pragma unroll
    for (int oo = 0; oo < OT; ++oo)
#pragma unroll
        for (int j = 0; j < 3; ++j) {
            au[oo][j][0] = 0.f; au[oo][j][1] = 0.f;
        }

    int c = 0;
    for (; c + 4 <= Cin; c += 4) {
        float2 xv[4][3];
#pragma unroll
        for (int cc = 0; cc < 4; ++cc)
#pragma unroll
            for (int j = 0; j < 3; ++j)
                xv[cc][j] = *(const float2*)(Xp + ((size_t)(c + cc) * 3 + j) * N);
#pragma unroll
        for (int oo = 0; oo < OT; ++oo) {
            float4 w4 = *(const float4*)&wsm[oo][c];
            float wv[4] = {w4.x, w4.y, w4.z, w4.w};
#pragma unroll
            for (int j = 0; j < 3; ++j) {
#pragma unroll
                for (int cc = 0; cc < 4; ++cc) {
                    au[oo][j][0] += wv[cc] * xv[cc][j].x;
                    au[oo][j][1] += wv[cc] * xv[cc][j].y;
                }
            }
        }
    }
    for (; c < Cin; ++c) {
        float2 xv[3];
#pragma unroll
        for (int j = 0; j < 3; ++j)
            xv[j] = *(const float2*)(Xp + ((size_t)c * 3 + j) * N);
#pragma unroll
        for (int oo = 0; oo < OT; ++oo) {
            float wv = wsm[oo][c];
#pragma unroll
            for (int j = 0; j < 3; ++j) {
                au[oo][j][0] += wv * xv[j].x;
                au[oo][j][1] += wv * xv[j].y;
            }
        }
    }
#pragma unroll
    for (int oo = 0; oo < OT; ++oo) {
        int o = o0 + oo;
        if (o < CoutE) {
#pragma unroll
            for (int j = 0; j < 3; ++j) {
                float2 st; st.x = au[oo][j][0]; st.y = au[oo][j][1];
                *(float2*)&Up[(((size_t)b * CoutE + o) * 3 + j) * N + n] = st;
            }
        }
    }
}

// ---------------- layer-5 stats (deterministic): one block per channel ----------------
__global__ void k_stats_plain_det(const float* __restrict__ U, float* __restrict__ mv,
                                  int N, int Cout, int BN, float cnt) {
    int o = blockIdx.x;
    int tid = threadIdx.x;
    float s1 = 0.f, s2 = 0.f;
    for (int g = tid; g < BN; g += 256) {
        int b = g / N, n = g % N;
        const float* Ub = U + (((size_t)b * Cout + o) * 3) * N;
        float p0 = Ub[n], p1 = Ub[(size_t)N + n], p2 = Ub[(size_t)2 * N + n];
        float nm = sqrtf(p0 * p0 + p1 * p1 + p2 * p2) + EPSV;
        s1 += nm;
        s2 += nm * nm;
    }
    __shared__ float r1[256], r2[256];
    r1[tid] = s1; r2[tid] = s2;
    __syncthreads();
    for (int st = 128; st > 0; st >>= 1) {
        if (tid < st) { r1[tid] += r1[tid + st]; r2[tid] += r2[tid + st]; }
        __syncthreads();
    }
    if (tid == 0) {
        float mu = r1[0] / cnt;
        float var = r2[0] / cnt - mu * mu;
        mv[2 * o] = mu;
        mv[2 * o + 1] = rsqrtf(var + 1e-5f);
    }
}

// ---------------- layer-5 final: BN + dir leaky (1 dir channel) -> d_out ----------------
__global__ void k_final_plain(const float* __restrict__ U, const float* __restrict__ Dv,
                              const float* __restrict__ mv,
                              const float* __restrict__ gamma, const float* __restrict__ beta,
                              float* __restrict__ out, int N, int Cout) {
    int b = blockIdx.z, o = blockIdx.y, tid = threadIdx.x;
    int n = blockIdx.x * 256 + tid;
    float mu = mv[2 * o];
    float inv = mv[2 * o + 1];
    float g = gamma[o], bt = beta[o];

    const float* Ub = U + (((size_t)b * Cout + o) * 3) * N;
    float p0 = Ub[n], p1 = Ub[(size_t)N + n], p2 = Ub[(size_t)2 * N + n];
    float nm = sqrtf(p0 * p0 + p1 * p1 + p2 * p2) + EPSV;
    float nbn = (nm - mu) * inv * g + bt;
    float sc = nbn / nm;
    p0 *= sc; p1 *= sc; p2 *= sc;

    float d0 = Dv[((size_t)b * 3 + 0) * N + n];
    float d1 = Dv[((size_t)b * 3 + 1) * N + n];
    float d2 = Dv[((size_t)b * 3 + 2) * N + n];
    float dot = p0 * d0 + p1 * d1 + p2 * d2;
    float o0, o1, o2;
    if (dot >= 0.f) {
        o0 = p0; o1 = p1; o2 = p2;
    } else {
        float f = dot / (d0 * d0 + d1 * d1 + d2 * d2 + EPSV);
        o0 = NS * p0 + (1.f - NS) * (p0 - f * d0);
        o1 = NS * p1 + (1.f - NS) * (p1 - f * d1);
        o2 = NS * p2 + (1.f - NS) * (p2 - f * d2);
    }
    size_t ob = (((size_t)b * Cout + o) * 3) * N + n;
    out[ob] = o0;
    out[ob + (size_t)N] = o1;
    out[ob + (size_t)2 * N] = o2;
}

extern "C" void kernel_launch(void* const* d_in, const int* in_sizes, int n_in,
                              void* d_out, int out_size, void* d_ws, size_t ws_size,
                              hipStream_t stream) {
    (void)in_sizes; (void)n_in; (void)out_size; (void)ws_size;
    const int B = 8, N = 1024;

    const float* x = (const float*)d_in[0];
    const float* W[5]; const float* Dw[5]; const float* G[5]; const float* Bt[5];
    for (int l = 0; l < 5; ++l) {
        W[l]  = (const float*)d_in[1 + 4 * l];
        Dw[l] = (const float*)d_in[2 + 4 * l];
        G[l]  = (const float*)d_in[3 + 4 * l];
        Bt[l] = (const float*)d_in[4 + 4 * l];
    }

    float* ws = (float*)d_ws;
    size_t off = 0;
    float* xt = ws + off;     off += (size_t)B * 3 * N;
    int* idx = (int*)(ws + off); off += (size_t)B * N * KNN;
    float* catp = ws + off;   off += (size_t)B * N * CROW;
    float* catn = ws + off;   off += (size_t)B * N * CROW;
    float* Up = ws + off;     off += (size_t)B * N * 85 * 3;
    float* Vp = ws + off;     off += (size_t)B * N * 85 * 3;
    float* UDp = ws + off;    off += (size_t)B * N * 85 * 3;
    float* VDp = ws + off;    off += (size_t)B * N * 85 * 3;
    float* U5 = ws + off;     off += (size_t)B * 341 * 3 * N;
    float* d5buf = ws + off;  off += (size_t)B * 3 * N;
    float* xx = ws + off;     off += (size_t)B * N;           // 16B-aligned (all prior multiples of 4)
    float* partials = ws + off; off += (size_t)341 * SSPLIT * 2;
    float* mv = ws + off;     off += 2 * 341;

    k_transpose<<<(B * N + 255) / 256, 256, 0, stream>>>(x, xt, xx, B, N);

    const int Cin_[4]  = {1, 21, 21, 42};
    const int Cout_[4] = {21, 21, 42, 85};
    const int inOff_[4] = {-1, 0, 21, 42};
    const int outOff_[4] = {0, 21, 42, 84};
    const int Tile_[4] = {32, 32, 32, 8};   // LDS budget: L4 needs small x-tile

    const int BN = B * N;

    for (int l = 0; l < 4; ++l) {
        int C = Cin_[l], Co = Cout_[l];
        int D = C * 3;
        int CoP = (Co + 3) & ~3;
        int TILE = Tile_[l];

        // n-major source for knn
        const float* Xn; long bs, so;
        if (inOff_[l] < 0) { Xn = xt; bs = (long)3 * N; so = 0; }
        else { Xn = catn; bs = (long)CROW * N; so = (long)inOff_[l] * 3 * N; }

        // point-major source for matmul
        const float* Xp; int rs, co;
        if (inOff_[l] < 0) { Xp = x; rs = 3; co = 0; }
        else { Xp = catp; rs = CROW; co = inOff_[l] * 3; }

        // xx for this layer was produced by k_transpose (l=0) or the previous
        // layer's k_final_fused (l>=1)
        dim3 gk(N / QT, B);
        k_knn<<<gk, 256, 0, stream>>>(Xn, xx, idx, N, D, bs, so);

        size_t smemB = (size_t)(4 * C * CoP + TILE * C * 3) * sizeof(float);
        k_matmul_pair_lds<<<(B * N) / TILE, 256, smemB, stream>>>(
            Xp, W[l], Dw[l], Up, Vp, UDp, VDp, C, Co, CoP, TILE, rs, co);

        dim3 gst(Co, SSPLIT);
        k_stats_edge_det<<<gst, 256, 0, stream>>>(Up, Vp, idx, partials, N, Co, BN);

        int doSq = (l < 3) ? 1 : 0;   // layers 0-2 produce xx for the next layer
        dim3 gf(N / TN, B);
        k_final_fused<<<gf, 256, 0, stream>>>(
            Up, Vp, UDp, VDp, idx, partials, G[l], Bt[l],
            catp, catn, xx, N, Co, outOff_[l] * 3,
            (float)((size_t)BN * KNN), doSq);
    }

    // layer 5 (reads catn n-major); W and Dw matmuls merged into one launch
    {
        long bs = (long)CROW * N, so = 0;
        dim3 gm5(N / 512, (341 + OT - 1) / OT + 1, B);   // +1: Dw tile
        k_matmul_plain<<<gm5, 256, 0, stream>>>(catn, W[4], Dw[4], U5, d5buf,
                                                N, 169, 341, bs, so);
        k_stats_plain_det<<<341, 256, 0, stream>>>(U5, mv, N, 341, BN, (float)BN);
        dim3 gs5(N / 256, 341, B);
        k_final_plain<<<gs5, 256, 0, stream>>>(U5, d5buf, mv, G[4], Bt[4],
                                               (float*)d_out, N, 341);
    }
}

// Round 11
// 653.712 us; speedup vs baseline: 1.1807x; 1.0166x over previous
//
#include <hip/hip_runtime.h>
#include <math.h>

#define KNN 20
#define NS 0.2f
#define EPSV 1e-6f
#define QT 4
#define OT 8
#define TN 8       // n-tile of k_final_fused
#define CROW 507   // 169*3, cat row stride (floats)
#define SSPLIT 8   // stats splits (== B; split s covers batch s exactly)

struct F3 { float x, y, z; };   // 12-byte vector load (global_load_dwordx3)

extern __shared__ __align__(16) float smem[];

// ---------------- transpose (B,N,3) -> (B,3,N) + fused sqnorm (layer-1) ----------------
__global__ void k_transpose(const float* __restrict__ x, float* __restrict__ xt,
                            float* __restrict__ xx, int B, int N) {
    int i = blockIdx.x * blockDim.x + threadIdx.x;
    if (i >= B * N) return;
    int b = i / N, n = i % N;
    const float* src = x + (size_t)(b * N + n) * 3;
    float* dst = xt + (size_t)b * 3 * N + n;
    float s0 = src[0], s1 = src[1], s2 = src[2];
    dst[0] = s0;
    dst[(size_t)N] = s1;
    dst[(size_t)2 * N] = s2;
    float s = 0.f;
    s += s0 * s0;
    s += s1 * s1;
    s += s2 * s2;
    xx[i] = s;
}

// ---------------- fused knn + pair-matmul launch ----------------
// Blocks [0, mmBlocks) run the pair-matmul body; blocks [mmBlocks, ...) run
// knn, each handling qPerBlock queries (qPerBlock/QT sequential passes).
// knn fills ~half the residency slots (1024 blocks when qPerBlock=8), so the
// mm blocks execute concurrently in knn's shadow instead of serializing.
// All per-query / per-point math verbatim from R10 -> bit-identical.
__global__ void k_knn_mm(// knn args
                         const float* __restrict__ Xn, const float* __restrict__ xx,
                         int* __restrict__ idx, int N, int D,
                         long batchStride, long sliceOff, int qPerBlock,
                         // mm args
                         const float* __restrict__ Xp, const float* __restrict__ W,
                         const float* __restrict__ Dw,
                         float* __restrict__ U, float* __restrict__ V,
                         float* __restrict__ UD, float* __restrict__ VD,
                         int C, int Co, int CoP, int TILE,
                         int rowStride, int colOff, int mmBlocks) {
    float* sm = smem;
    int tid = threadIdx.x;

    if ((int)blockIdx.x < mmBlocks) {
        // ---------------- pair-matmul body (verbatim math) ----------------
        const int CP = C * CoP;
        float* wts = sm;            // 4*CP
        float* xs = sm + 4 * CP;    // TILE * C * 3
        int bn0 = blockIdx.x * TILE;
        int C3 = C * 3;

        int npad = CoP - Co;
        if (npad) {
            for (int t = tid; t < 4 * C * npad; t += 256) {
                int q = t / npad, oo = Co + t % npad;
                int mat = q / C, c = q % C;
                wts[mat * CP + c * CoP + oo] = 0.f;
            }
        }
        int twoCC = 2 * C * Co;
        for (int t = tid; t < twoCC; t += 256) {
            int o = t / (2 * C), c = t % (2 * C);
            float w = W[t], dw = Dw[t];
            if (c < C) {
                wts[c * CoP + o] = w;
                wts[2 * CP + c * CoP + o] = dw;
            } else {
                wts[CP + (c - C) * CoP + o] = w;
                wts[3 * CP + (c - C) * CoP + o] = dw;
            }
        }
        for (int t = tid; t < TILE * C3; t += 256) {
            int p = t / C3, cc = t % C3;
            xs[t] = Xp[(size_t)(bn0 + p) * rowStride + colOff + cc];
        }
        __syncthreads();
        for (int t = tid; t < CP; t += 256) {
            wts[CP + t] -= wts[t];
            wts[3 * CP + t] -= wts[2 * CP + t];
        }
        __syncthreads();

        int GPP = CoP >> 2;
        int items = TILE * GPP;
        for (int e = tid; e < items; e += 256) {
            int p = e / GPP, og = e - p * GPP;
            int o0 = og * 4;
            const float* xr = xs + p * C3;

            float aU[4][3], aV[4][3], aDu[4][3], aDv[4][3];
#pragma unroll
            for (int i = 0; i < 4; ++i)
#pragma unroll
                for (int j = 0; j < 3; ++j) {
                    aU[i][j] = 0.f; aV[i][j] = 0.f; aDu[i][j] = 0.f; aDv[i][j] = 0.f;
                }

            for (int c = 0; c < C; ++c) {
                float x0 = xr[c * 3], x1 = xr[c * 3 + 1], x2 = xr[c * 3 + 2];
                const float* wp = wts + c * CoP + o0;
                float4 wa4 = *(const float4*)(wp);
                float4 wb4 = *(const float4*)(wp + CP);
                float4 da4 = *(const float4*)(wp + 2 * CP);
                float4 db4 = *(const float4*)(wp + 3 * CP);
                float wav[4] = {wa4.x, wa4.y, wa4.z, wa4.w};
                float wbv[4] = {wb4.x, wb4.y, wb4.z, wb4.w};
                float dav[4] = {da4.x, da4.y, da4.z, da4.w};
                float dbv[4] = {db4.x, db4.y, db4.z, db4.w};
#pragma unroll
                for (int i = 0; i < 4; ++i) {
                    aU[i][0] += wav[i] * x0; aU[i][1] += wav[i] * x1; aU[i][2] += wav[i] * x2;
                    aV[i][0] += wbv[i] * x0; aV[i][1] += wbv[i] * x1; aV[i][2] += wbv[i] * x2;
                    aDu[i][0] += dav[i] * x0; aDu[i][1] += dav[i] * x1; aDu[i][2] += dav[i] * x2;
                    aDv[i][0] += dbv[i] * x0; aDv[i][1] += dbv[i] * x1; aDv[i][2] += dbv[i] * x2;
                }
            }

            size_t base = ((size_t)(bn0 + p) * Co + o0) * 3;
#pragma unroll
            for (int i = 0; i < 4; ++i) {
                int o = o0 + i;
                if (o < Co) {
                    size_t off = base + (size_t)i * 3;
                    U[off] = aU[i][0]; U[off + 1] = aU[i][1]; U[off + 2] = aU[i][2];
                    V[off] = aV[i][0]; V[off + 1] = aV[i][1]; V[off + 2] = aV[i][2];
                    UD[off] = aDu[i][0]; UD[off + 1] = aDu[i][1]; UD[off + 2] = aDu[i][2];
                    VD[off] = aDv[i][0]; VD[off + 1] = aDv[i][1]; VD[off + 2] = aDv[i][2];
                }
            }
        }
        return;
    }

    // ---------------- knn body (R10 selection, verbatim math) ----------------
    int kb = (int)blockIdx.x - mmBlocks;
    int qbpb = N / qPerBlock;            // q-blocks per batch
    int b = kb / qbpb;
    int qbase = (kb - b * qbpb) * qPerBlock;
    int lane = tid & 63;
    int wave = tid >> 6;

    float* qf = sm;                      // 128*QT floats
    float* pdb = sm + 128 * QT;          // QT*1024 floats

    const float* Xb = Xn + (size_t)b * batchStride + sliceOff;
    const float* xxb = xx + (size_t)b * N;

    for (int q0 = qbase; q0 < qbase + qPerBlock; q0 += QT) {
        for (int t = tid; t < QT * D; t += 256) {
            int d = t >> 2, q = t & 3;
            qf[d * QT + q] = Xb[(size_t)d * N + (q0 + q)];
        }
        __syncthreads();

        float a0x = 0.f, a0y = 0.f, a0z = 0.f, a0w = 0.f;
        float a1x = 0.f, a1y = 0.f, a1z = 0.f, a1w = 0.f;
        float a2x = 0.f, a2y = 0.f, a2z = 0.f, a2w = 0.f;
        float a3x = 0.f, a3y = 0.f, a3z = 0.f, a3w = 0.f;

        const float* mbase = Xb + 4 * tid;
#pragma unroll 3
        for (int d = 0; d < D; ++d) {
            float4 xm = *(const float4*)(mbase + (size_t)d * N);
            float4 qv = *(const float4*)(qf + d * QT);
            a0x += qv.x * xm.x; a0y += qv.x * xm.y; a0z += qv.x * xm.z; a0w += qv.x * xm.w;
            a1x += qv.y * xm.x; a1y += qv.y * xm.y; a1z += qv.y * xm.z; a1w += qv.y * xm.w;
            a2x += qv.z * xm.x; a2y += qv.z * xm.y; a2z += qv.z * xm.z; a2w += qv.z * xm.w;
            a3x += qv.w * xm.x; a3y += qv.w * xm.y; a3z += qv.w * xm.z; a3w += qv.w * xm.w;
        }

        {
            float4 m2 = *(const float4*)(xxb + 4 * tid);
            float4 qn = *(const float4*)(xxb + q0);
            float4 v;
            v.x = 2.f * a0x - qn.x - m2.x; v.y = 2.f * a0y - qn.x - m2.y;
            v.z = 2.f * a0z - qn.x - m2.z; v.w = 2.f * a0w - qn.x - m2.w;
            *(float4*)(pdb + 0 * 1024 + 4 * tid) = v;
            v.x = 2.f * a1x - qn.y - m2.x; v.y = 2.f * a1y - qn.y - m2.y;
            v.z = 2.f * a1z - qn.y - m2.z; v.w = 2.f * a1w - qn.y - m2.w;
            *(float4*)(pdb + 1 * 1024 + 4 * tid) = v;
            v.x = 2.f * a2x - qn.z - m2.x; v.y = 2.f * a2y - qn.z - m2.y;
            v.z = 2.f * a2z - qn.z - m2.z; v.w = 2.f * a2w - qn.z - m2.w;
            *(float4*)(pdb + 2 * 1024 + 4 * tid) = v;
            v.x = 2.f * a3x - qn.w - m2.x; v.y = 2.f * a3y - qn.w - m2.y;
            v.z = 2.f * a3z - qn.w - m2.z; v.w = 2.f * a3w - qn.w - m2.w;
            *(float4*)(pdb + 3 * 1024 + 4 * tid) = v;
        }
        __syncthreads();

        // ---- sortable keys: hi = orderable(float bits), lo = 1023 - idx ----
        unsigned long long key[16];
#pragma unroll
        for (int t = 0; t < 16; ++t) {
            unsigned u = __float_as_uint(pdb[wave * 1024 + t * 64 + lane]);
            u ^= (unsigned)((int)u >> 31) | 0x80000000u;
            unsigned lo = (unsigned)(1023 - t * 64) - (unsigned)lane;
            key[t] = ((unsigned long long)u << 32) | (unsigned long long)lo;
        }

        // ---- explicit Batcher odd-even mergesort n=16 (descending) ----
#define CE(a, b)                                        \
        {                                               \
            unsigned long long ka = key[a], kb2 = key[b]; \
            bool sw = ka < kb2;                         \
            key[a] = sw ? kb2 : ka;                     \
            key[b] = sw ? ka : kb2;                     \
        }
        CE(0,1) CE(2,3) CE(4,5) CE(6,7) CE(8,9) CE(10,11) CE(12,13) CE(14,15)
        CE(0,2) CE(1,3) CE(4,6) CE(5,7) CE(8,10) CE(9,11) CE(12,14) CE(13,15)
        CE(1,2) CE(5,6) CE(9,10) CE(13,14)
        CE(0,4) CE(1,5) CE(2,6) CE(3,7) CE(8,12) CE(9,13) CE(10,14) CE(11,15)
        CE(2,4) CE(3,5) CE(10,12) CE(11,13)
        CE(1,2) CE(3,4) CE(5,6) CE(9,10) CE(11,12) CE(13,14)
        CE(0,8) CE(1,9) CE(2,10) CE(3,11) CE(4,12) CE(5,13) CE(6,14) CE(7,15)
        CE(4,8) CE(5,9) CE(6,10) CE(7,11)
        CE(2,4) CE(3,5) CE(6,8) CE(7,9) CE(10,12) CE(11,13)
        CE(1,2) CE(3,4) CE(5,6) CE(7,8) CE(9,10) CE(11,12) CE(13,14)
#undef CE

        // ---- spill keys 8..15 to pdb[wave]'s row (dead after key build) ----
        __syncthreads();   // fence float reads vs u64 writes
        unsigned long long* kl = (unsigned long long*)(pdb + wave * 1024);
#pragma unroll
        for (int t = 8; t < 16; ++t) kl[(t - 8) * 64 + lane] = key[t];
        int nspill = 0;

        // ---- 20 extractions: hi butterfly + ballot resolve + owner pop ----
        long outBase = ((long)b * N + q0 + wave) * KNN;
        for (int it = 0; it < KNN; ++it) {
            unsigned myh = (unsigned)(key[0] >> 32);
            unsigned mylo = (unsigned)(key[0] & 0xFFFFFFFFull);
            unsigned bh = myh;
#pragma unroll
            for (int off = 32; off >= 1; off >>= 1) {
                unsigned oh = __shfl_xor(bh, off, 64);
                if (oh > bh) bh = oh;
            }
            unsigned long long mask = __ballot(myh == bh);
            unsigned ml;
            if (__popcll(mask) == 1) {
                int src = (int)(__ffsll((long long)mask) - 1);
                ml = __shfl(mylo, src, 64);
            } else {
                unsigned cand = (myh == bh) ? mylo : 0u;
#pragma unroll
                for (int off = 32; off >= 1; off >>= 1) {
                    unsigned oc = __shfl_xor(cand, off, 64);
                    if (oc > cand) cand = oc;
                }
                ml = cand;
            }
            int bi = 1023 - (int)(ml & 1023u);
            if (lane == 0) idx[outBase + it] = bi;
            if ((bi & 63) == lane) {
                key[0] = key[1]; key[1] = key[2]; key[2] = key[3]; key[3] = key[4];
                key[4] = key[5]; key[5] = key[6]; key[6] = key[7];
                int sidx = nspill < 8 ? nspill : 7;
                unsigned long long nv = kl[sidx * 64 + lane];
                key[7] = (nspill < 8) ? nv : 0ull;
                nspill++;
            }
        }
        __syncthreads();   // protect qf/pd reuse across q-block passes
    }
}

// ---------------- LDS-staged point-major pair matmul (layer 4 only: 62KB LDS) ----------
__global__ void k_matmul_pair_lds(const float* __restrict__ X, const float* __restrict__ W,
                                  const float* __restrict__ Dw,
                                  float* __restrict__ U, float* __restrict__ V,
                                  float* __restrict__ UD, float* __restrict__ VD,
                                  int C, int Co, int CoP, int TILE,
                                  int rowStride, int colOff) {
    const int CP = C * CoP;
    float* wts = smem;
    float* xs = smem + 4 * CP;

    int tid = threadIdx.x;
    int bn0 = blockIdx.x * TILE;
    int C3 = C * 3;

    int npad = CoP - Co;
    if (npad) {
        for (int t = tid; t < 4 * C * npad; t += 256) {
            int q = t / npad, oo = Co + t % npad;
            int mat = q / C, c = q % C;
            wts[mat * CP + c * CoP + oo] = 0.f;
        }
    }
    int twoCC = 2 * C * Co;
    for (int t = tid; t < twoCC; t += 256) {
        int o = t / (2 * C), c = t % (2 * C);
        float w = W[t], dw = Dw[t];
        if (c < C) {
            wts[c * CoP + o] = w;
            wts[2 * CP + c * CoP + o] = dw;
        } else {
            wts[CP + (c - C) * CoP + o] = w;
            wts[3 * CP + (c - C) * CoP + o] = dw;
        }
    }
    for (int t = tid; t < TILE * C3; t += 256) {
        int p = t / C3, cc = t % C3;
        xs[t] = X[(size_t)(bn0 + p) * rowStride + colOff + cc];
    }
    __syncthreads();
    for (int t = tid; t < CP; t += 256) {
        wts[CP + t] -= wts[t];
        wts[3 * CP + t] -= wts[2 * CP + t];
    }
    __syncthreads();

    int GPP = CoP >> 2;
    int items = TILE * GPP;
    for (int e = tid; e < items; e += 256) {
        int p = e / GPP, og = e - p * GPP;
        int o0 = og * 4;
        const float* xr = xs + p * C3;

        float aU[4][3], aV[4][3], aDu[4][3], aDv[4][3];
#pragma unroll
        for (int i = 0; i < 4; ++i)
#pragma unroll
            for (int j = 0; j < 3; ++j) {
                aU[i][j] = 0.f; aV[i][j] = 0.f; aDu[i][j] = 0.f; aDv[i][j] = 0.f;
            }

        for (int c = 0; c < C; ++c) {
            float x0 = xr[c * 3], x1 = xr[c * 3 + 1], x2 = xr[c * 3 + 2];
            const float* wp = wts + c * CoP + o0;
            float4 wa4 = *(const float4*)(wp);
            float4 wb4 = *(const float4*)(wp + CP);
            float4 da4 = *(const float4*)(wp + 2 * CP);
            float4 db4 = *(const float4*)(wp + 3 * CP);
            float wav[4] = {wa4.x, wa4.y, wa4.z, wa4.w};
            float wbv[4] = {wb4.x, wb4.y, wb4.z, wb4.w};
            float dav[4] = {da4.x, da4.y, da4.z, da4.w};
            float dbv[4] = {db4.x, db4.y, db4.z, db4.w};
#pragma unroll
            for (int i = 0; i < 4; ++i) {
                aU[i][0] += wav[i] * x0; aU[i][1] += wav[i] * x1; aU[i][2] += wav[i] * x2;
                aV[i][0] += wbv[i] * x0; aV[i][1] += wbv[i] * x1; aV[i][2] += wbv[i] * x2;
                aDu[i][0] += dav[i] * x0; aDu[i][1] += dav[i] * x1; aDu[i][2] += dav[i] * x2;
                aDv[i][0] += dbv[i] * x0; aDv[i][1] += dbv[i] * x1; aDv[i][2] += dbv[i] * x2;
            }
        }

        size_t base = ((size_t)(bn0 + p) * Co + o0) * 3;
#pragma unroll
        for (int i = 0; i < 4; ++i) {
            int o = o0 + i;
            if (o < Co) {
                size_t off = base + (size_t)i * 3;
                U[off] = aU[i][0]; U[off + 1] = aU[i][1]; U[off + 2] = aU[i][2];
                V[off] = aV[i][0]; V[off + 1] = aV[i][1]; V[off + 2] = aV[i][2];
                UD[off] = aDu[i][0]; UD[off + 1] = aDu[i][1]; UD[off + 2] = aDu[i][2];
                VD[off] = aDv[i][0]; VD[off + 1] = aDv[i][1]; VD[off + 2] = aDv[i][2];
            }
        }
    }
}

// ---------------- BN stats stage A (deterministic, R5 order + LDS staging) ----------------
__global__ void k_stats_edge_det(const float* __restrict__ U, const float* __restrict__ V,
                                 const int* __restrict__ idx, float* __restrict__ partials,
                                 int N, int Co, int BN) {
    int o = blockIdx.x;
    int s = blockIdx.y;
    int tid = threadIdx.x;
    int P = BN / SSPLIT;      // == N == 1024
    int g0 = s * P;

    __shared__ float Ush[3072];   // N * 3 (channel-o vectors for batch s)
    __shared__ float r1[256], r2[256];

    for (int t = tid; t < P; t += 256) {
        F3 u3 = *(const F3*)(U + ((size_t)(g0 + t) * Co + o) * 3);
        Ush[t * 3 + 0] = u3.x;
        Ush[t * 3 + 1] = u3.y;
        Ush[t * 3 + 2] = u3.z;
    }
    __syncthreads();

    float s1 = 0.f, s2 = 0.f;
    for (int pl = tid; pl < P; pl += 256) {
        int g = g0 + pl;                       // flattened b*N+n
        F3 v3 = *(const F3*)(V + ((size_t)g * Co + o) * 3);
        float v0 = v3.x, v1 = v3.y, v2 = v3.z;
        const int* ip = idx + (size_t)g * KNN;
        for (int kk = 0; kk < KNN; ++kk) {
            const float* Ur = Ush + ip[kk] * 3;   // idx is batch-local
            float p0 = Ur[0] + v0;
            float p1 = Ur[1] + v1;
            float p2 = Ur[2] + v2;
            float nm = sqrtf(p0 * p0 + p1 * p1 + p2 * p2) + EPSV;
            s1 += nm;
            s2 += nm * nm;
        }
    }
    r1[tid] = s1; r2[tid] = s2;
    __syncthreads();
    for (int st = 128; st > 0; st >>= 1) {
        if (tid < st) { r1[tid] += r1[tid + st]; r2[tid] += r2[tid + st]; }
        __syncthreads();
    }
    if (tid == 0) {
        partials[(o * SSPLIT + s) * 2] = r1[0];
        partials[(o * SSPLIT + s) * 2 + 1] = r2[0];
    }
}

// ---------------- fused stage-B: BN + dir leaky + mean-pool + cat transpose + sqnorm ----
__global__ void k_final_fused(const float* __restrict__ U, const float* __restrict__ V,
                              const float* __restrict__ UD, const float* __restrict__ VD,
                              const int* __restrict__ idx, const float* __restrict__ partials,
                              const float* __restrict__ gamma, const float* __restrict__ beta,
                              float* __restrict__ catp, float* __restrict__ catn,
                              float* __restrict__ xx,
                              int N, int Co, int colOff, float cnt, int doSq) {
    int b = blockIdx.y;
    int n0 = blockIdx.x * TN;
    int tid = threadIdx.x;
    int CC = Co * 3;

    __shared__ float tile[TN * 255];    // TN x CC, CC <= 255
    __shared__ float muS[85], invS[85];

    for (int o = tid; o < Co; o += 256) {
        float s1 = 0.f, s2 = 0.f;
        for (int s = 0; s < SSPLIT; ++s) {
            s1 += partials[(o * SSPLIT + s) * 2];
            s2 += partials[(o * SSPLIT + s) * 2 + 1];
        }
        float mu = s1 / cnt;
        float var = s2 / cnt - mu * mu;
        muS[o] = mu;
        invS[o] = rsqrtf(var + 1e-5f);
    }
    __syncthreads();

    const float invk = 1.f / (float)KNN;
    int items = TN * Co;
    for (int e = tid; e < items; e += 256) {
        int nl = e / Co, o = e - nl * Co;
        int n = n0 + nl;
        float mu = muS[o], inv = invS[o];
        float gmm = gamma[o], bt = beta[o];

        size_t ctr = ((size_t)(b * N + n) * Co + o) * 3;
        F3 vc = *(const F3*)(V + ctr);
        F3 wc = *(const F3*)(VD + ctr);
        float v0 = vc.x, v1 = vc.y, v2 = vc.z;
        float w0 = wc.x, w1 = wc.y, w2 = wc.z;
        const int* ip = idx + ((size_t)b * N + n) * KNN;

        float a0 = 0.f, a1 = 0.f, a2 = 0.f;
        for (int kk = 0; kk < KNN; ++kk) {
            int m = ip[kk];
            size_t nb = ((size_t)(b * N + m) * Co + o) * 3;
            F3 un = *(const F3*)(U + nb);
            F3 dn = *(const F3*)(UD + nb);
            float p0 = un.x + v0;
            float p1 = un.y + v1;
            float p2 = un.z + v2;
            float nm = sqrtf(p0 * p0 + p1 * p1 + p2 * p2) + EPSV;
            float nbn = (nm - mu) * inv * gmm + bt;
            float sc = nbn / nm;
            p0 *= sc; p1 *= sc; p2 *= sc;
            float d0 = dn.x + w0;
            float d1 = dn.y + w1;
            float d2 = dn.z + w2;
            float dot = p0 * d0 + p1 * d1 + p2 * d2;
            if (dot >= 0.f) {
                a0 += p0; a1 += p1; a2 += p2;
            } else {
                float f = dot / (d0 * d0 + d1 * d1 + d2 * d2 + EPSV);
                a0 += NS * p0 + (1.f - NS) * (p0 - f * d0);
                a1 += NS * p1 + (1.f - NS) * (p1 - f * d1);
                a2 += NS * p2 + (1.f - NS) * (p2 - f * d2);
            }
        }
        tile[nl * CC + o * 3 + 0] = a0 * invk;
        tile[nl * CC + o * 3 + 1] = a1 * invk;
        tile[nl * CC + o * 3 + 2] = a2 * invk;
    }
    __syncthreads();

    for (int t = tid; t < TN * CC; t += 256) {
        int nl = t / CC, c = t - nl * CC;
        catp[(size_t)(b * N + n0 + nl) * CROW + colOff + c] = tile[nl * CC + c];
    }
    for (int t = tid; t < TN * CC; t += 256) {
        int c = t >> 3, nl = t & (TN - 1);   // TN == 8
        catn[(size_t)b * CROW * N + (size_t)(colOff + c) * N + n0 + nl] = tile[nl * CC + c];
    }
    if (doSq && tid < TN) {
        const float* row = tile + tid * CC;
        float s = 0.f;
        for (int c = 0; c < CC; ++c) {
            float v = row[c];
            s += v * v;
        }
        xx[(size_t)b * N + n0 + tid] = s;
    }
}

// ---------------- plain matmul (layer 5, n-major): U = W*x, j-fused + 2-n tile ----------
__global__ void k_matmul_plain(const float* __restrict__ X, const float* __restrict__ W,
                               const float* __restrict__ Dw,
                               float* __restrict__ U, float* __restrict__ Ud,
                               int N, int Cin, int Cout, long batchStride, long sliceOff) {
    int ot = blockIdx.y;
    int b = blockIdx.z;
    int tid = threadIdx.x;
    int n = blockIdx.x * 512 + 2 * tid;

    const float* Wp; float* Up; int CoutE; int o0;
    if (ot == (int)gridDim.y - 1) {   // Dw path
        Wp = Dw; Up = Ud; CoutE = 1; o0 = 0;
    } else {
        Wp = W; Up = U; CoutE = Cout; o0 = ot * OT;
    }

    __shared__ __align__(16) float wsm[OT][176];
    for (int t = tid; t < OT * Cin; t += 256) {
        int oo = t / Cin, c = t % Cin;
        int o = o0 + oo;
        wsm[oo][c] = (o < CoutE) ? Wp[(size_t)o * Cin + c] : 0.f;
    }
    __syncthreads();

    const float* Xp = X + (size_t)b * batchStride + sliceOff + n;
    float au[OT][3][2];
#pragma unroll
    for (int oo = 0; oo < OT; ++oo)
#pragma unroll
        for (int j = 0; j < 3; ++j) {
            au[oo][j][0] = 0.f; au[oo][j][1] = 0.f;
        }

    int c = 0;
    for (; c + 4 <= Cin; c += 4) {
        float2 xv[4][3];
#pragma unroll
        for (int cc = 0; cc < 4; ++cc)
#pragma unroll
            for (int j = 0; j < 3; ++j)
                xv[cc][j] = *(const float2*)(Xp + ((size_t)(c + cc) * 3 + j) * N);
#pragma unroll
        for (int oo = 0; oo < OT; ++oo) {
            float4 w4 = *(const float4*)&wsm[oo][c];
            float wv[4] = {w4.x, w4.y, w4.z, w4.w};
#pragma unroll
            for (int j = 0; j < 3; ++j) {
#pragma unroll
                for (int cc = 0; cc < 4; ++cc) {
                    au[oo][j][0] += wv[cc] * xv[cc][j].x;
                    au[oo][j][1] += wv[cc] * xv[cc][j].y;
                }
            }
        }
    }
    for (; c < Cin; ++c) {
        float2 xv[3];
#pragma unroll
        for (int j = 0; j < 3; ++j)
            xv[j] = *(const float2*)(Xp + ((size_t)c * 3 + j) * N);
#pragma unroll
        for (int oo = 0; oo < OT; ++oo) {
            float wv = wsm[oo][c];
#pragma unroll
            for (int j = 0; j < 3; ++j) {
                au[oo][j][0] += wv * xv[j].x;
                au[oo][j][1] += wv * xv[j].y;
            }
        }
    }
#pragma unroll
    for (int oo = 0; oo < OT; ++oo) {
        int o = o0 + oo;
        if (o < CoutE) {
#pragma unroll
            for (int j = 0; j < 3; ++j) {
                float2 st; st.x = au[oo][j][0]; st.y = au[oo][j][1];
                *(float2*)&Up[(((size_t)b * CoutE + o) * 3 + j) * N + n] = st;
            }
        }
    }
}

// ---------------- layer-5 stats (deterministic): one block per channel ----------------
__global__ void k_stats_plain_det(const float* __restrict__ U, float* __restrict__ mv,
                                  int N, int Cout, int BN, float cnt) {
    int o = blockIdx.x;
    int tid = threadIdx.x;
    float s1 = 0.f, s2 = 0.f;
    for (int g = tid; g < BN; g += 256) {
        int b = g / N, n = g % N;
        const float* Ub = U + (((size_t)b * Cout + o) * 3) * N;
        float p0 = Ub[n], p1 = Ub[(size_t)N + n], p2 = Ub[(size_t)2 * N + n];
        float nm = sqrtf(p0 * p0 + p1 * p1 + p2 * p2) + EPSV;
        s1 += nm;
        s2 += nm * nm;
    }
    __shared__ float r1[256], r2[256];
    r1[tid] = s1; r2[tid] = s2;
    __syncthreads();
    for (int st = 128; st > 0; st >>= 1) {
        if (tid < st) { r1[tid] += r1[tid + st]; r2[tid] += r2[tid + st]; }
        __syncthreads();
    }
    if (tid == 0) {
        float mu = r1[0] / cnt;
        float var = r2[0] / cnt - mu * mu;
        mv[2 * o] = mu;
        mv[2 * o + 1] = rsqrtf(var + 1e-5f);
    }
}

// ---------------- layer-5 final: BN + dir leaky (1 dir channel) -> d_out ----------------
__global__ void k_final_plain(const float* __restrict__ U, const float* __restrict__ Dv,
                              const float* __restrict__ mv,
                              const float* __restrict__ gamma, const float* __restrict__ beta,
                              float* __restrict__ out, int N, int Cout) {
    int b = blockIdx.z, o = blockIdx.y, tid = threadIdx.x;
    int n = blockIdx.x * 256 + tid;
    float mu = mv[2 * o];
    float inv = mv[2 * o + 1];
    float g = gamma[o], bt = beta[o];

    const float* Ub = U + (((size_t)b * Cout + o) * 3) * N;
    float p0 = Ub[n], p1 = Ub[(size_t)N + n], p2 = Ub[(size_t)2 * N + n];
    float nm = sqrtf(p0 * p0 + p1 * p1 + p2 * p2) + EPSV;
    float nbn = (nm - mu) * inv * g + bt;
    float sc = nbn / nm;
    p0 *= sc; p1 *= sc; p2 *= sc;

    float d0 = Dv[((size_t)b * 3 + 0) * N + n];
    float d1 = Dv[((size_t)b * 3 + 1) * N + n];
    float d2 = Dv[((size_t)b * 3 + 2) * N + n];
    float dot = p0 * d0 + p1 * d1 + p2 * d2;
    float o0, o1, o2;
    if (dot >= 0.f) {
        o0 = p0; o1 = p1; o2 = p2;
    } else {
        float f = dot / (d0 * d0 + d1 * d1 + d2 * d2 + EPSV);
        o0 = NS * p0 + (1.f - NS) * (p0 - f * d0);
        o1 = NS * p1 + (1.f - NS) * (p1 - f * d1);
        o2 = NS * p2 + (1.f - NS) * (p2 - f * d2);
    }
    size_t ob = (((size_t)b * Cout + o) * 3) * N + n;
    out[ob] = o0;
    out[ob + (size_t)N] = o1;
    out[ob + (size_t)2 * N] = o2;
}

extern "C" void kernel_launch(void* const* d_in, const int* in_sizes, int n_in,
                              void* d_out, int out_size, void* d_ws, size_t ws_size,
                              hipStream_t stream) {
    (void)in_sizes; (void)n_in; (void)out_size; (void)ws_size;
    const int B = 8, N = 1024;

    const float* x = (const float*)d_in[0];
    const float* W[5]; const float* Dw[5]; const float* G[5]; const float* Bt[5];
    for (int l = 0; l < 5; ++l) {
        W[l]  = (const float*)d_in[1 + 4 * l];
        Dw[l] = (const float*)d_in[2 + 4 * l];
        G[l]  = (const float*)d_in[3 + 4 * l];
        Bt[l] = (const float*)d_in[4 + 4 * l];
    }

    float* ws = (float*)d_ws;
    size_t off = 0;
    float* xt = ws + off;     off += (size_t)B * 3 * N;
    int* idx = (int*)(ws + off); off += (size_t)B * N * KNN;
    float* catp = ws + off;   off += (size_t)B * N * CROW;
    float* catn = ws + off;   off += (size_t)B * N * CROW;
    float* Up = ws + off;     off += (size_t)B * N * 85 * 3;
    float* Vp = ws + off;     off += (size_t)B * N * 85 * 3;
    float* UDp = ws + off;    off += (size_t)B * N * 85 * 3;
    float* VDp = ws + off;    off += (size_t)B * N * 85 * 3;
    float* U5 = ws + off;     off += (size_t)B * 341 * 3 * N;
    float* d5buf = ws + off;  off += (size_t)B * 3 * N;
    float* xx = ws + off;     off += (size_t)B * N;
    float* partials = ws + off; off += (size_t)341 * SSPLIT * 2;
    float* mv = ws + off;     off += 2 * 341;

    k_transpose<<<(B * N + 255) / 256, 256, 0, stream>>>(x, xt, xx, B, N);

    const int Cin_[4]  = {1, 21, 21, 42};
    const int Cout_[4] = {21, 21, 42, 85};
    const int inOff_[4] = {-1, 0, 21, 42};
    const int outOff_[4] = {0, 21, 42, 84};
    const int Tile_[4] = {32, 32, 16, 8};   // L3 TILE=16 to fit fused-LDS; L4 separate

    const int BN = B * N;
    const size_t KNN_LDS = (size_t)(128 * QT + QT * 1024) * sizeof(float);   // 18432

    for (int l = 0; l < 4; ++l) {
        int C = Cin_[l], Co = Cout_[l];
        int D = C * 3;
        int CoP = (Co + 3) & ~3;
        int TILE = Tile_[l];

        const float* Xn; long bs, so;
        if (inOff_[l] < 0) { Xn = xt; bs = (long)3 * N; so = 0; }
        else { Xn = catn; bs = (long)CROW * N; so = (long)inOff_[l] * 3 * N; }

        const float* Xp; int rs, co;
        if (inOff_[l] < 0) { Xp = x; rs = 3; co = 0; }
        else { Xp = catp; rs = CROW; co = inOff_[l] * 3; }

        size_t mmNeed = (size_t)(4 * C * CoP + TILE * C * 3) * sizeof(float);

        if (l < 3) {
            // fused: mm blocks first (overlap in knn's shadow), knn 8 queries/block
            int mmB = BN / TILE;
            int knnB = BN / 8;               // qPerBlock = 8
            size_t smemB = mmNeed > KNN_LDS ? mmNeed : KNN_LDS;
            k_knn_mm<<<mmB + knnB, 256, smemB, stream>>>(
                Xn, xx, idx, N, D, bs, so, 8,
                Xp, W[l], Dw[l], Up, Vp, UDp, VDp, C, Co, CoP, TILE, rs, co, mmB);
        } else {
            // L4: knn alone (qPerBlock=4, full 2048 blocks), mm separate (62KB LDS)
            k_knn_mm<<<BN / 4, 256, KNN_LDS, stream>>>(
                Xn, xx, idx, N, D, bs, so, 4,
                Xp, W[l], Dw[l], Up, Vp, UDp, VDp, C, Co, CoP, TILE, rs, co, 0);
            k_matmul_pair_lds<<<BN / TILE, 256, mmNeed, stream>>>(
                Xp, W[l], Dw[l], Up, Vp, UDp, VDp, C, Co, CoP, TILE, rs, co);
        }

        dim3 gst(Co, SSPLIT);
        k_stats_edge_det<<<gst, 256, 0, stream>>>(Up, Vp, idx, partials, N, Co, BN);

        int doSq = (l < 3) ? 1 : 0;
        dim3 gf(N / TN, B);
        k_final_fused<<<gf, 256, 0, stream>>>(
            Up, Vp, UDp, VDp, idx, partials, G[l], Bt[l],
            catp, catn, xx, N, Co, outOff_[l] * 3,
            (float)((size_t)BN * KNN), doSq);
    }

    // layer 5 (reads catn n-major); W and Dw matmuls merged into one launch
    {
        long bs = (long)CROW * N, so = 0;
        dim3 gm5(N / 512, (341 + OT - 1) / OT + 1, B);   // +1: Dw tile
        k_matmul_plain<<<gm5, 256, 0, stream>>>(catn, W[4], Dw[4], U5, d5buf,
                                                N, 169, 341, bs, so);
        k_stats_plain_det<<<341, 256, 0, stream>>>(U5, mv, N, 341, BN, (float)BN);
        dim3 gs5(N / 256, 341, B);
        k_final_plain<<<gs5, 256, 0, stream>>>(U5, d5buf, mv, G[4], Bt[4],
                                               (float*)d_out, N, 341);
    }
}